// Round 11
// baseline (196.002 us; speedup 1.0000x reference)
//
#include <hip/hip_runtime.h>
#include <hip/hip_bf16.h>
#include <math.h>

#define BB   2
#define CC   256
#define NN   4096
#define DTXT 512
#define OO   256
#define HH   4
#define HDD  64

typedef __attribute__((ext_vector_type(4))) unsigned short us4;
typedef __attribute__((ext_vector_type(8))) short          bf16x8;
typedef __attribute__((ext_vector_type(4))) float          f32x4;
typedef __attribute__((ext_vector_type(2))) unsigned int   u32x2;

__device__ __forceinline__ float b2f(unsigned short u) {
    union { unsigned int i; float f; } x; x.i = ((unsigned int)u) << 16; return x.f;
}
__device__ __forceinline__ unsigned short f2b(float f) {
    union { float f; unsigned int i; } x; x.f = f;
    unsigned int r = (x.i + 0x7FFFu + ((x.i >> 16) & 1u)) >> 16;
    return (unsigned short)r;
}
__device__ __forceinline__ unsigned int cvtpk(float lo, float hi) {
    unsigned int r;
    asm volatile("v_cvt_pk_bf16_f32 %0, %1, %2" : "=v"(r) : "v"(lo), "v"(hi));
    return r;
}
__device__ __forceinline__ float loadIn(const void* p, size_t i, bool f32) {
    return f32 ? ((const float*)p)[i] : b2f(((const unsigned short*)p)[i]);
}
__device__ __forceinline__ bf16x8 loadFrag(const void* p, size_t off, bool f32) {
    if (!f32) return *(const bf16x8*)((const unsigned short*)p + off);
    const float* q = (const float*)p + off;
    f32x4 a = *(const f32x4*)q, b = *(const f32x4*)(q + 4);
    bf16x8 r;
    r[0] = (short)f2b(a[0]); r[1] = (short)f2b(a[1]);
    r[2] = (short)f2b(a[2]); r[3] = (short)f2b(a[3]);
    r[4] = (short)f2b(b[0]); r[5] = (short)f2b(b[1]);
    r[6] = (short)f2b(b[2]); r[7] = (short)f2b(b[3]);
    return r;
}
__device__ __forceinline__ bool inIsF32(const void* gammaP) {
    return ((const unsigned short*)gammaP)[0] == 0;
}

// ---------- kernel 1: fused text-proj+GELU and transpose (unchanged) ----------
__global__ void __launch_bounds__(256) k_tf(const void* __restrict__ point,
                     const void* __restrict__ text,
                     const void* __restrict__ Wt,
                     const void* __restrict__ bt,
                     const void* __restrict__ gammaP,
                     unsigned short* __restrict__ xtp,
                     unsigned short* __restrict__ xtf) {
    bool f32in = inIsF32(gammaP);
    __shared__ float txt[DTXT];
    __shared__ float tv[64];
    __shared__ unsigned short tile[64][72];
    int b = blockIdx.z, c0 = blockIdx.y * 64, n0 = blockIdx.x * 64;
    int tid = threadIdx.x;
    int w = tid >> 6, l = tid & 63;

    for (int i = tid; i < DTXT; i += 256) txt[i] = loadIn(text, (size_t)b * DTXT + i, f32in);
    __syncthreads();
    {
        int c = c0 + w * 16 + (l >> 2);
        int q4 = (l & 3) * 128;
        float acc = 0.f;
        for (int it = 0; it < 128; it += 4) {
            int i = q4 + it;
            if (f32in) {
                f32x4 wv = *(const f32x4*)((const float*)Wt + (size_t)c * DTXT + i);
#pragma unroll
                for (int j = 0; j < 4; ++j) acc += wv[j] * txt[i + j];
            } else {
                us4 wv = *(const us4*)((const unsigned short*)Wt + (size_t)c * DTXT + i);
#pragma unroll
                for (int j = 0; j < 4; ++j) acc += b2f(wv[j]) * txt[i + j];
            }
        }
        acc += __shfl_xor(acc, 1);
        acc += __shfl_xor(acc, 2);
        if ((l & 3) == 0) {
            acc += loadIn(bt, c, f32in);
            tv[w * 16 + (l >> 2)] = 0.5f * acc * (1.f + erff(acc * 0.70710678118654752f));
        }
    }
#pragma unroll
    for (int it = 0; it < 2; ++it) {
        int cl = tid / 8 + it * 32;
        int nl = (tid % 8) * 8;
        size_t off = ((size_t)(b * CC + c0 + cl)) * NN + n0 + nl;
        unsigned short u[8];
        if (f32in) {
            const float* s = (const float*)point + off;
            f32x4 v0 = *(const f32x4*)s, v1 = *(const f32x4*)(s + 4);
#pragma unroll
            for (int j = 0; j < 4; ++j) { u[j] = f2b(v0[j]); u[4 + j] = f2b(v1[j]); }
        } else {
            const unsigned short* s = (const unsigned short*)point + off;
            us4 v0 = *(const us4*)s, v1 = *(const us4*)(s + 4);
#pragma unroll
            for (int j = 0; j < 4; ++j) { u[j] = v0[j]; u[4 + j] = v1[j]; }
        }
#pragma unroll
        for (int j = 0; j < 8; ++j) tile[cl][nl + j] = u[j];
    }
    __syncthreads();
#pragma unroll
    for (int it = 0; it < 2; ++it) {
        int nl = tid / 8 + it * 32;
        int cl = (tid % 8) * 8;
        size_t base = ((size_t)(b * NN + n0 + nl)) * CC + c0 + cl;
        us4 a0, a1, f0, f1;
#pragma unroll
        for (int j = 0; j < 4; ++j) {
            unsigned short u = tile[cl + j][nl];
            a0[j] = u; f0[j] = f2b(b2f(u) + tv[cl + j]);
        }
#pragma unroll
        for (int j = 0; j < 4; ++j) {
            unsigned short u = tile[cl + 4 + j][nl];
            a1[j] = u; f1[j] = f2b(b2f(u) + tv[cl + 4 + j]);
        }
        *(us4*)(xtp + base) = a0; *(us4*)(xtp + base + 4) = a1;
        *(us4*)(xtf + base) = f0; *(us4*)(xtf + base + 4) = f1;
    }
}

// ---------- one-wave 64x64 NT-GEMM tile body (unchanged) ----------
__device__ __forceinline__ void gemm_tile64(
        const void* A, bool fA, const void* Bm, bool fB,
        const void* bias, bool biasRow, bool f32in, bool relu,
        int rowW, int colW, int K, int ldc,
        unsigned short* co, int l) {
    int lr = l & 15, lh = l >> 4;
    f32x4 acc[4][4] = {};
    for (int k0 = 0; k0 < K; k0 += 32) {
        bf16x8 af[4], bfr[4];
#pragma unroll
        for (int mi = 0; mi < 4; ++mi)
            af[mi] = loadFrag(A, (size_t)(rowW + mi * 16 + lr) * K + k0 + 8 * lh, fA);
#pragma unroll
        for (int ni = 0; ni < 4; ++ni)
            bfr[ni] = loadFrag(Bm, (size_t)(colW + ni * 16 + lr) * K + k0 + 8 * lh, fB);
#pragma unroll
        for (int mi = 0; mi < 4; ++mi)
#pragma unroll
            for (int ni = 0; ni < 4; ++ni)
                acc[mi][ni] = __builtin_amdgcn_mfma_f32_16x16x32_bf16(af[mi], bfr[ni], acc[mi][ni], 0, 0, 0);
    }
#pragma unroll
    for (int mi = 0; mi < 4; ++mi)
#pragma unroll
        for (int ni = 0; ni < 4; ++ni)
#pragma unroll
            for (int r = 0; r < 4; ++r) {
                int row = rowW + mi * 16 + lh * 4 + r;
                int col = colW + ni * 16 + lr;
                float v = acc[mi][ni][r] + loadIn(bias, biasRow ? row : col, f32in);
                if (relu) v = fmaxf(v, 0.f);
                co[(size_t)row * ldc + col] = f2b(v);
            }
}

// ---------- kernel 2: fused Q/K/V projections (unchanged) ----------
__global__ void __launch_bounds__(64) k_qkv(
        const unsigned short* __restrict__ XTp,
        const unsigned short* __restrict__ XTf,
        const void* __restrict__ Wq, const void* __restrict__ bq,
        const void* __restrict__ Wk, const void* __restrict__ bk,
        const void* __restrict__ Wv, const void* __restrict__ bv,
        const void* __restrict__ gammaP,
        unsigned short* __restrict__ QT,
        unsigned short* __restrict__ KT,
        unsigned short* __restrict__ Vb) {
    bool f32in = inIsF32(gammaP);
    int bid = blockIdx.x, l = threadIdx.x;
    if (bid < 1024) {
        int t = bid & 511;
        bool isQ = bid < 512;
        int rowW = (t >> 2) * 64, colW = (t & 3) * 64;
        gemm_tile64(isQ ? XTp : XTf, false,
                    isQ ? Wq : Wk, f32in,
                    isQ ? bq : bk, false, f32in, false,
                    rowW, colW, CC, OO,
                    isQ ? QT : KT, l);
    } else {
        int t = bid - 1024;
        int b = t >> 8, r = t & 255;
        int rowW = (r & 3) * 64, colW = (r >> 2) * 64;
        gemm_tile64(Wv, f32in,
                    XTp + (size_t)b * NN * CC, false,
                    bv, true, f32in, false,
                    rowW, colW, CC, NN,
                    Vb + (size_t)b * OO * NN, l);
    }
}

// ---------- kernel 3: flash attention v8 ----------
// QBLK=128 (4 waves x 32 q), single-buffered K/V LDS (36.8 KB -> 4 blocks/CU),
// reg-staged issue-early/write-late with 2 barriers/tile. SPLIT-way KV-split.
// exp2/fma softmax, defer-max, l via ones-MFMA.
template<int SPLIT>
__global__ void __launch_bounds__(256) k_attn(const unsigned short* __restrict__ QT,
                                              const unsigned short* __restrict__ KT,
                                              const unsigned short* __restrict__ Vb,
                                              float* __restrict__ Opart,
                                              float* __restrict__ mlb,
                                              unsigned short* __restrict__ AT) {
    const int NT = NN / SPLIT / 64;
    const float L2E = 1.44269504088896f;
    const float THR = 5.54517744448f;          // 8*ln2
    int n0 = blockIdx.x * 128;
    int bh = blockIdx.y;
    int b = bh >> 2, h = bh & 3;
    int sp = blockIdx.z;
    int kbase = sp * (NN / SPLIT);
    int tid = threadIdx.x;
    int w = tid >> 6, l = tid & 63, lr = l & 15, lh = l >> 4;

    __shared__ unsigned short Kl[64 * 72];
    __shared__ unsigned short Vl[64 * 72];
    __shared__ unsigned short Pl[4][32 * 72];

    const size_t qkBase = (size_t)b * NN * OO + h * HDD;
    const size_t vBase  = ((size_t)b * OO + h * HDD) * NN;

    const unsigned short* qrow0 = QT + qkBase + (size_t)(n0 + w * 32 + lr) * OO;
    const unsigned short* qrow1 = qrow0 + (size_t)16 * OO;
    bf16x8 qf00 = *(const bf16x8*)(qrow0 + 8 * lh);
    bf16x8 qf01 = *(const bf16x8*)(qrow0 + 32 + 8 * lh);
    bf16x8 qf10 = *(const bf16x8*)(qrow1 + 8 * lh);
    bf16x8 qf11 = *(const bf16x8*)(qrow1 + 32 + 8 * lh);

    int srow = tid >> 3;
    int scol = (tid & 7) * 8;
    const unsigned short* Kg = KT + qkBase + (size_t)(kbase + srow) * OO + scol;
    const unsigned short* Vg = Vb + vBase + (size_t)srow * NN + kbase + scol;
    int ldsW0 = srow * 72 + scol, ldsW1 = (srow + 32) * 72 + scol;

    bf16x8 ones;
#pragma unroll
    for (int j = 0; j < 8; ++j) ones[j] = (short)0x3F80;   // bf16 1.0

    f32x4 oacc[2][4] = {};
    f32x4 lacc[2] = {};
    float mrun0 = -1e30f, mrun1 = -1e30f;
    const f32x4 zero = {0.f, 0.f, 0.f, 0.f};
    unsigned short* plw = &Pl[w][0];

    {   // prologue: tile 0
        bf16x8 ka0 = *(const bf16x8*)Kg;
        bf16x8 ka1 = *(const bf16x8*)(Kg + (size_t)32 * OO);
        bf16x8 va0 = *(const bf16x8*)Vg;
        bf16x8 va1 = *(const bf16x8*)(Vg + (size_t)32 * NN);
        *(bf16x8*)&Kl[ldsW0] = ka0; *(bf16x8*)&Kl[ldsW1] = ka1;
        *(bf16x8*)&Vl[ldsW0] = va0; *(bf16x8*)&Vl[ldsW1] = va1;
    }
    __syncthreads();

    for (int t = 0; t < NT; ++t) {
        bf16x8 ka0, ka1, va0, va1;
        if (t < NT - 1) {   // issue next-tile loads early (T14)
            const unsigned short* kg = Kg + (size_t)(t + 1) * 64 * OO;
            const unsigned short* vg = Vg + (t + 1) * 64;
            ka0 = *(const bf16x8*)kg;
            ka1 = *(const bf16x8*)(kg + (size_t)32 * OO);
            va0 = *(const bf16x8*)vg;
            va1 = *(const bf16x8*)(vg + (size_t)32 * NN);
        }
        // QK^T: K frag read once, used by both q-halves
        f32x4 S0[4], S1[4];
#pragma unroll
        for (int s = 0; s < 4; ++s) {
            const unsigned short* kb = &Kl[(16 * s + lr) * 72 + 8 * lh];
            bf16x8 k0 = *(const bf16x8*)kb;
            bf16x8 k1 = *(const bf16x8*)(kb + 32);
            S0[s] = __builtin_amdgcn_mfma_f32_16x16x32_bf16(k0, qf00, zero, 0, 0, 0);
            S0[s] = __builtin_amdgcn_mfma_f32_16x16x32_bf16(k1, qf01, S0[s], 0, 0, 0);
            S1[s] = __builtin_amdgcn_mfma_f32_16x16x32_bf16(k0, qf10, zero, 0, 0, 0);
            S1[s] = __builtin_amdgcn_mfma_f32_16x16x32_bf16(k1, qf11, S1[s], 0, 0, 0);
        }
        // softmax, q-half 0
        {
            float tm = -1e30f;
#pragma unroll
            for (int s = 0; s < 4; ++s)
                tm = fmaxf(tm, fmaxf(fmaxf(S0[s][0], S0[s][1]), fmaxf(S0[s][2], S0[s][3])));
            tm = fmaxf(tm, __shfl_xor(tm, 16));
            tm = fmaxf(tm, __shfl_xor(tm, 32));
            if (__any(tm > mrun0 + THR)) {
                float mn = fmaxf(mrun0, tm);
                float sc = exp2f((mrun0 - mn) * L2E);
                lacc[0] *= sc;
#pragma unroll
                for (int dt = 0; dt < 4; ++dt) oacc[0][dt] *= sc;
                mrun0 = mn;
            }
            float mL = mrun0 * L2E;
#pragma unroll
            for (int s = 0; s < 4; ++s) {
                float p0 = exp2f(__builtin_fmaf(S0[s][0], L2E, -mL));
                float p1 = exp2f(__builtin_fmaf(S0[s][1], L2E, -mL));
                float p2 = exp2f(__builtin_fmaf(S0[s][2], L2E, -mL));
                float p3 = exp2f(__builtin_fmaf(S0[s][3], L2E, -mL));
                u32x2 v; v[0] = cvtpk(p0, p1); v[1] = cvtpk(p2, p3);
                *(u32x2*)(plw + lr * 72 + s * 16 + 4 * lh) = v;
            }
        }
        // softmax, q-half 1
        {
            float tm = -1e30f;
#pragma unroll
            for (int s = 0; s < 4; ++s)
                tm = fmaxf(tm, fmaxf(fmaxf(S1[s][0], S1[s][1]), fmaxf(S1[s][2], S1[s][3])));
            tm = fmaxf(tm, __shfl_xor(tm, 16));
            tm = fmaxf(tm, __shfl_xor(tm, 32));
            if (__any(tm > mrun1 + THR)) {
                float mn = fmaxf(mrun1, tm);
                float sc = exp2f((mrun1 - mn) * L2E);
                lacc[1] *= sc;
#pragma unroll
                for (int dt = 0; dt < 4; ++dt) oacc[1][dt] *= sc;
                mrun1 = mn;
            }
            float mL = mrun1 * L2E;
#pragma unroll
            for (int s = 0; s < 4; ++s) {
                float p0 = exp2f(__builtin_fmaf(S1[s][0], L2E, -mL));
                float p1 = exp2f(__builtin_fmaf(S1[s][1], L2E, -mL));
                float p2 = exp2f(__builtin_fmaf(S1[s][2], L2E, -mL));
                float p3 = exp2f(__builtin_fmaf(S1[s][3], L2E, -mL));
                u32x2 v; v[0] = cvtpk(p0, p1); v[1] = cvtpk(p2, p3);
                *(u32x2*)(plw + (16 + lr) * 72 + s * 16 + 4 * lh) = v;
            }
        }
        // PV + l: V frag read once, used by both q-halves
#pragma unroll
        for (int c = 0; c < 2; ++c) {
            bf16x8 pf0 = *(const bf16x8*)(plw + lr * 72 + c * 32 + 8 * lh);
            bf16x8 pf1 = *(const bf16x8*)(plw + (16 + lr) * 72 + c * 32 + 8 * lh);
            lacc[0] = __builtin_amdgcn_mfma_f32_16x16x32_bf16(ones, pf0, lacc[0], 0, 0, 0);
            lacc[1] = __builtin_amdgcn_mfma_f32_16x16x32_bf16(ones, pf1, lacc[1], 0, 0, 0);
#pragma unroll
            for (int dt = 0; dt < 4; ++dt) {
                bf16x8 vf = *(const bf16x8*)&Vl[(dt * 16 + lr) * 72 + c * 32 + 8 * lh];
                oacc[0][dt] = __builtin_amdgcn_mfma_f32_16x16x32_bf16(vf, pf0, oacc[0][dt], 0, 0, 0);
                oacc[1][dt] = __builtin_amdgcn_mfma_f32_16x16x32_bf16(vf, pf1, oacc[1][dt], 0, 0, 0);
            }
        }
        // single-buffer swap: all waves done reading -> overwrite
        __syncthreads();
        if (t < NT - 1) {
            *(bf16x8*)&Kl[ldsW0] = ka0; *(bf16x8*)&Kl[ldsW1] = ka1;
            *(bf16x8*)&Vl[ldsW0] = va0; *(bf16x8*)&Vl[ldsW1] = va1;
        }
        __syncthreads();
    }

#pragma unroll
    for (int h2 = 0; h2 < 2; ++h2) {
        float mrun = h2 ? mrun1 : mrun0;
        float lrun = lacc[h2][0];
        int nrow = n0 + w * 32 + 16 * h2 + lr;
        if (SPLIT == 1) {
            float invL = 1.f / lrun;
            unsigned short* orow = AT + ((size_t)b * NN + nrow) * OO + h * HDD;
#pragma unroll
            for (int dt = 0; dt < 4; ++dt) {
                us4 res;
#pragma unroll
                for (int r = 0; r < 4; ++r) res[r] = f2b(oacc[h2][dt][r] * invL);
                *(us4*)(orow + dt * 16 + 4 * lh) = res;
            }
        } else {
            size_t rbase = ((size_t)(b * HH + h) * SPLIT + sp) * NN + nrow;
#pragma unroll
            for (int dt = 0; dt < 4; ++dt)
                *(f32x4*)(Opart + rbase * HDD + dt * 16 + 4 * lh) = oacc[h2][dt];
            if (lh == 0) { mlb[rbase * 2] = mrun; mlb[rbase * 2 + 1] = lrun; }
        }
    }
}

// ---------- kernel 3b: merge SPLIT KV-split partials ----------
template<int SPLIT>
__global__ void __launch_bounds__(256) k_amerge(const float* __restrict__ Opart,
                                                const float* __restrict__ mlb,
                                                unsigned short* __restrict__ AT) {
    int n0 = blockIdx.x * 64, bb = blockIdx.y;
    int h = threadIdx.x >> 6, l = threadIdx.x & 63;
    int n = n0 + l;
    size_t bs[SPLIT];
    float mv[SPLIT], lv[SPLIT], ev[SPLIT];
    float M = -1e30f;
#pragma unroll
    for (int s = 0; s < SPLIT; ++s) {
        bs[s] = ((size_t)(bb * HH + h) * SPLIT + s) * NN + n;
        mv[s] = mlb[bs[s] * 2]; lv[s] = mlb[bs[s] * 2 + 1];
        M = fmaxf(M, mv[s]);
    }
    float L = 0.f;
#pragma unroll
    for (int s = 0; s < SPLIT; ++s) { ev[s] = expf(mv[s] - M); L += lv[s] * ev[s]; }
    float invL = 1.f / L;
    unsigned short* orow = AT + ((size_t)(bb * NN + n)) * OO + h * HDD;
#pragma unroll
    for (int dt = 0; dt < 16; ++dt) {
        float acc[4] = {0.f, 0.f, 0.f, 0.f};
#pragma unroll
        for (int s = 0; s < SPLIT; ++s) {
            f32x4 a = *(const f32x4*)(Opart + bs[s] * HDD + 4 * dt);
#pragma unroll
            for (int r = 0; r < 4; ++r) acc[r] += a[r] * ev[s];
        }
        us4 o;
#pragma unroll
        for (int r = 0; r < 4; ++r) o[r] = f2b(acc[r] * invL);
        *(us4*)(orow + 4 * dt) = o;
    }
}

// ---------- kernel 4: MLP1 (unchanged) ----------
__global__ void __launch_bounds__(64) k_mlp1(
        const unsigned short* __restrict__ AT,
        const void* __restrict__ W1, const void* __restrict__ b1,
        const void* __restrict__ gammaP,
        unsigned short* __restrict__ X1) {
    bool f32in = inIsF32(gammaP);
    int bid = blockIdx.x, l = threadIdx.x;
    int rowW = (bid >> 2) * 64, colW = (bid & 3) * 64;
    gemm_tile64(AT, false, W1, f32in, b1, false, f32in, true,
                rowW, colW, OO, OO, X1, l);
}

// ---------- kernel 5: MLP2 + gamma*x + point epilogue (unchanged) ----------
__global__ void __launch_bounds__(64) k_mlp2f(
        const unsigned short* __restrict__ X1,
        const void* __restrict__ W2, const void* __restrict__ b2,
        const void* __restrict__ point,
        const void* __restrict__ gammaP,
        void* __restrict__ outP) {
    bool f32in = inIsF32(gammaP);
    float g = loadIn(gammaP, 0, f32in);
    int bid = blockIdx.x, l = threadIdx.x;
    int lr = l & 15, lh = l >> 4;
    int rowW = (bid >> 2) * 64, colW = (bid & 3) * 64;
    f32x4 acc[4][4] = {};
    for (int k0 = 0; k0 < OO; k0 += 32) {
        bf16x8 af[4], bfr[4];
#pragma unroll
        for (int mi = 0; mi < 4; ++mi)
            af[mi] = *(const bf16x8*)(X1 + (size_t)(rowW + mi * 16 + lr) * OO + k0 + 8 * lh);
#pragma unroll
        for (int ni = 0; ni < 4; ++ni)
            bfr[ni] = loadFrag(W2, (size_t)(colW + ni * 16 + lr) * OO + k0 + 8 * lh, f32in);
#pragma unroll
        for (int mi = 0; mi < 4; ++mi)
#pragma unroll
            for (int ni = 0; ni < 4; ++ni)
                acc[mi][ni] = __builtin_amdgcn_mfma_f32_16x16x32_bf16(af[mi], bfr[ni], acc[mi][ni], 0, 0, 0);
    }
    int b = rowW >> 12;
#pragma unroll
    for (int mi = 0; mi < 4; ++mi)
#pragma unroll
        for (int ni = 0; ni < 4; ++ni) {
            int n = (rowW & (NN - 1)) + mi * 16 + lh * 4;
            int o = colW + ni * 16 + lr;
            size_t base = (size_t)b * OO * NN + (size_t)o * NN + n;
            float bia = loadIn(b2, o, f32in);
            if (f32in) {
                const f32x4 pv = *(const f32x4*)((const float*)point + base);
                f32x4 wv;
#pragma unroll
                for (int r = 0; r < 4; ++r) wv[r] = g * (acc[mi][ni][r] + bia) + pv[r];
                *(f32x4*)((float*)outP + base) = wv;
            } else {
                const us4 pv = *(const us4*)((const unsigned short*)point + base);
                us4 wv;
#pragma unroll
                for (int r = 0; r < 4; ++r) wv[r] = f2b(g * (acc[mi][ni][r] + bia) + b2f(pv[r]));
                *(us4*)((unsigned short*)outP + base) = wv;
            }
        }
}

extern "C" void kernel_launch(void* const* d_in, const int* in_sizes, int n_in,
                              void* d_out, int out_size, void* d_ws, size_t ws_size,
                              hipStream_t stream) {
    (void)in_sizes; (void)n_in; (void)out_size;
    const void* point = d_in[0];
    const void* text  = d_in[1];
    const void* Wt    = d_in[2];
    const void* bt    = d_in[3];
    const void* Wq    = d_in[4];
    const void* bq    = d_in[5];
    const void* Wk    = d_in[6];
    const void* bk    = d_in[7];
    const void* Wv    = d_in[8];
    const void* bv    = d_in[9];
    const void* W1    = d_in[10];
    const void* b1    = d_in[11];
    const void* W2    = d_in[12];
    const void* b2    = d_in[13];
    const void* gamma = d_in[14];

    char* ws = (char*)d_ws;
    const size_t SZ = (size_t)BB * NN * CC;   // 2 Mi bf16 = 4 MiB
    unsigned short* XTp = (unsigned short*)(ws + 4096);
    unsigned short* XTf = XTp + SZ;
    unsigned short* QT  = XTf + SZ;
    unsigned short* Vb  = QT + SZ;
    unsigned short* KT  = Vb + SZ;
    unsigned short* X1  = XTf;                       // dead after k_qkv
    unsigned short* AT  = (unsigned short*)d_out;    // scratch; k_mlp2f rewrites d_out
    float* Opart = (float*)(KT + SZ);

    auto needFor = [&](int split) {
        return (size_t)4096 + 5 * SZ * 2
             + (size_t)BB * HH * split * NN * HDD * 4
             + (size_t)BB * HH * split * NN * 2 * 4;
    };

    k_tf<<<dim3(NN / 64, CC / 64, BB), 256, 0, stream>>>(point, text, Wt, bt, gamma, XTp, XTf);
    k_qkv<<<dim3(1536), 64, 0, stream>>>(XTp, XTf, Wq, bq, Wk, bk, Wv, bv, gamma, QT, KT, Vb);
    if (ws_size >= needFor(4)) {
        float* mlb = Opart + (size_t)BB * HH * 4 * NN * HDD;
        k_attn<4><<<dim3(NN / 128, BB * HH, 4), 256, 0, stream>>>(QT, KT, Vb, Opart, mlb, nullptr);
        k_amerge<4><<<dim3(NN / 64, BB), 256, 0, stream>>>(Opart, mlb, AT);
    } else if (ws_size >= needFor(2)) {
        float* mlb = Opart + (size_t)BB * HH * 2 * NN * HDD;
        k_attn<2><<<dim3(NN / 128, BB * HH, 2), 256, 0, stream>>>(QT, KT, Vb, Opart, mlb, nullptr);
        k_amerge<2><<<dim3(NN / 64, BB), 256, 0, stream>>>(Opart, mlb, AT);
    } else {
        k_attn<1><<<dim3(NN / 128, BB * HH, 1), 256, 0, stream>>>(QT, KT, Vb, nullptr, nullptr, AT);
    }
    k_mlp1<<<dim3(512), 64, 0, stream>>>(AT, W1, b1, gamma, X1);
    k_mlp2f<<<dim3(512), 64, 0, stream>>>(X1, W2, b2, point, gamma, d_out);
}

// Round 12
// 168.574 us; speedup vs baseline: 1.1627x; 1.1627x over previous
//
#include <hip/hip_runtime.h>
#include <hip/hip_bf16.h>
#include <math.h>

#define BB   2
#define CC   256
#define NN   4096
#define DTXT 512
#define OO   256
#define HH   4
#define HDD  64

typedef __attribute__((ext_vector_type(4))) unsigned short us4;
typedef __attribute__((ext_vector_type(8))) short          bf16x8;
typedef __attribute__((ext_vector_type(4))) float          f32x4;
typedef __attribute__((ext_vector_type(2))) unsigned int   u32x2;

__device__ __forceinline__ float b2f(unsigned short u) {
    union { unsigned int i; float f; } x; x.i = ((unsigned int)u) << 16; return x.f;
}
__device__ __forceinline__ unsigned short f2b(float f) {
    union { float f; unsigned int i; } x; x.f = f;
    unsigned int r = (x.i + 0x7FFFu + ((x.i >> 16) & 1u)) >> 16;
    return (unsigned short)r;
}
__device__ __forceinline__ unsigned int cvtpk(float lo, float hi) {
    unsigned int r;
    asm volatile("v_cvt_pk_bf16_f32 %0, %1, %2" : "=v"(r) : "v"(lo), "v"(hi));
    return r;
}
__device__ __forceinline__ float loadIn(const void* p, size_t i, bool f32) {
    return f32 ? ((const float*)p)[i] : b2f(((const unsigned short*)p)[i]);
}
__device__ __forceinline__ bf16x8 loadFrag(const void* p, size_t off, bool f32) {
    if (!f32) return *(const bf16x8*)((const unsigned short*)p + off);
    const float* q = (const float*)p + off;
    f32x4 a = *(const f32x4*)q, b = *(const f32x4*)(q + 4);
    bf16x8 r;
    r[0] = (short)f2b(a[0]); r[1] = (short)f2b(a[1]);
    r[2] = (short)f2b(a[2]); r[3] = (short)f2b(a[3]);
    r[4] = (short)f2b(b[0]); r[5] = (short)f2b(b[1]);
    r[6] = (short)f2b(b[2]); r[7] = (short)f2b(b[3]);
    return r;
}
__device__ __forceinline__ bool inIsF32(const void* gammaP) {
    return ((const unsigned short*)gammaP)[0] == 0;
}

// ---------- kernel 1: fused text-proj+GELU and transpose (unchanged) ----------
__global__ void __launch_bounds__(256) k_tf(const void* __restrict__ point,
                     const void* __restrict__ text,
                     const void* __restrict__ Wt,
                     const void* __restrict__ bt,
                     const void* __restrict__ gammaP,
                     unsigned short* __restrict__ xtp,
                     unsigned short* __restrict__ xtf) {
    bool f32in = inIsF32(gammaP);
    __shared__ float txt[DTXT];
    __shared__ float tv[64];
    __shared__ unsigned short tile[64][72];
    int b = blockIdx.z, c0 = blockIdx.y * 64, n0 = blockIdx.x * 64;
    int tid = threadIdx.x;
    int w = tid >> 6, l = tid & 63;

    for (int i = tid; i < DTXT; i += 256) txt[i] = loadIn(text, (size_t)b * DTXT + i, f32in);
    __syncthreads();
    {
        int c = c0 + w * 16 + (l >> 2);
        int q4 = (l & 3) * 128;
        float acc = 0.f;
        for (int it = 0; it < 128; it += 4) {
            int i = q4 + it;
            if (f32in) {
                f32x4 wv = *(const f32x4*)((const float*)Wt + (size_t)c * DTXT + i);
#pragma unroll
                for (int j = 0; j < 4; ++j) acc += wv[j] * txt[i + j];
            } else {
                us4 wv = *(const us4*)((const unsigned short*)Wt + (size_t)c * DTXT + i);
#pragma unroll
                for (int j = 0; j < 4; ++j) acc += b2f(wv[j]) * txt[i + j];
            }
        }
        acc += __shfl_xor(acc, 1);
        acc += __shfl_xor(acc, 2);
        if ((l & 3) == 0) {
            acc += loadIn(bt, c, f32in);
            tv[w * 16 + (l >> 2)] = 0.5f * acc * (1.f + erff(acc * 0.70710678118654752f));
        }
    }
#pragma unroll
    for (int it = 0; it < 2; ++it) {
        int cl = tid / 8 + it * 32;
        int nl = (tid % 8) * 8;
        size_t off = ((size_t)(b * CC + c0 + cl)) * NN + n0 + nl;
        unsigned short u[8];
        if (f32in) {
            const float* s = (const float*)point + off;
            f32x4 v0 = *(const f32x4*)s, v1 = *(const f32x4*)(s + 4);
#pragma unroll
            for (int j = 0; j < 4; ++j) { u[j] = f2b(v0[j]); u[4 + j] = f2b(v1[j]); }
        } else {
            const unsigned short* s = (const unsigned short*)point + off;
            us4 v0 = *(const us4*)s, v1 = *(const us4*)(s + 4);
#pragma unroll
            for (int j = 0; j < 4; ++j) { u[j] = v0[j]; u[4 + j] = v1[j]; }
        }
#pragma unroll
        for (int j = 0; j < 8; ++j) tile[cl][nl + j] = u[j];
    }
    __syncthreads();
#pragma unroll
    for (int it = 0; it < 2; ++it) {
        int nl = tid / 8 + it * 32;
        int cl = (tid % 8) * 8;
        size_t base = ((size_t)(b * NN + n0 + nl)) * CC + c0 + cl;
        us4 a0, a1, f0, f1;
#pragma unroll
        for (int j = 0; j < 4; ++j) {
            unsigned short u = tile[cl + j][nl];
            a0[j] = u; f0[j] = f2b(b2f(u) + tv[cl + j]);
        }
#pragma unroll
        for (int j = 0; j < 4; ++j) {
            unsigned short u = tile[cl + 4 + j][nl];
            a1[j] = u; f1[j] = f2b(b2f(u) + tv[cl + 4 + j]);
        }
        *(us4*)(xtp + base) = a0; *(us4*)(xtp + base + 4) = a1;
        *(us4*)(xtf + base) = f0; *(us4*)(xtf + base + 4) = f1;
    }
}

// ---------- one-wave 64x64 NT-GEMM tile body (unchanged) ----------
__device__ __forceinline__ void gemm_tile64(
        const void* A, bool fA, const void* Bm, bool fB,
        const void* bias, bool biasRow, bool f32in, bool relu,
        int rowW, int colW, int K, int ldc,
        unsigned short* co, int l) {
    int lr = l & 15, lh = l >> 4;
    f32x4 acc[4][4] = {};
    for (int k0 = 0; k0 < K; k0 += 32) {
        bf16x8 af[4], bfr[4];
#pragma unroll
        for (int mi = 0; mi < 4; ++mi)
            af[mi] = loadFrag(A, (size_t)(rowW + mi * 16 + lr) * K + k0 + 8 * lh, fA);
#pragma unroll
        for (int ni = 0; ni < 4; ++ni)
            bfr[ni] = loadFrag(Bm, (size_t)(colW + ni * 16 + lr) * K + k0 + 8 * lh, fB);
#pragma unroll
        for (int mi = 0; mi < 4; ++mi)
#pragma unroll
            for (int ni = 0; ni < 4; ++ni)
                acc[mi][ni] = __builtin_amdgcn_mfma_f32_16x16x32_bf16(af[mi], bfr[ni], acc[mi][ni], 0, 0, 0);
    }
#pragma unroll
    for (int mi = 0; mi < 4; ++mi)
#pragma unroll
        for (int ni = 0; ni < 4; ++ni)
#pragma unroll
            for (int r = 0; r < 4; ++r) {
                int row = rowW + mi * 16 + lh * 4 + r;
                int col = colW + ni * 16 + lr;
                float v = acc[mi][ni][r] + loadIn(bias, biasRow ? row : col, f32in);
                if (relu) v = fmaxf(v, 0.f);
                co[(size_t)row * ldc + col] = f2b(v);
            }
}

// ---------- kernel 2: fused Q/K/V projections (unchanged) ----------
__global__ void __launch_bounds__(64) k_qkv(
        const unsigned short* __restrict__ XTp,
        const unsigned short* __restrict__ XTf,
        const void* __restrict__ Wq, const void* __restrict__ bq,
        const void* __restrict__ Wk, const void* __restrict__ bk,
        const void* __restrict__ Wv, const void* __restrict__ bv,
        const void* __restrict__ gammaP,
        unsigned short* __restrict__ QT,
        unsigned short* __restrict__ KT,
        unsigned short* __restrict__ Vb) {
    bool f32in = inIsF32(gammaP);
    int bid = blockIdx.x, l = threadIdx.x;
    if (bid < 1024) {
        int t = bid & 511;
        bool isQ = bid < 512;
        int rowW = (t >> 2) * 64, colW = (t & 3) * 64;
        gemm_tile64(isQ ? XTp : XTf, false,
                    isQ ? Wq : Wk, f32in,
                    isQ ? bq : bk, false, f32in, false,
                    rowW, colW, CC, OO,
                    isQ ? QT : KT, l);
    } else {
        int t = bid - 1024;
        int b = t >> 8, r = t & 255;
        int rowW = (r & 3) * 64, colW = (r >> 2) * 64;
        gemm_tile64(Wv, f32in,
                    XTp + (size_t)b * NN * CC, false,
                    bv, true, f32in, false,
                    rowW, colW, CC, NN,
                    Vb + (size_t)b * OO * NN, l);
    }
}

// ---------- kernel 3: flash attention (R10 config: QBLK=128, dbuf, SPLIT-way) ----------
template<int SPLIT>
__global__ void __launch_bounds__(256) k_attn(const unsigned short* __restrict__ QT,
                                              const unsigned short* __restrict__ KT,
                                              const unsigned short* __restrict__ Vb,
                                              float* __restrict__ Opart,
                                              float* __restrict__ mlb,
                                              unsigned short* __restrict__ AT) {
    const int NT = NN / SPLIT / 64;
    const float L2E = 1.44269504088896f;
    const float THR = 5.54517744448f;          // 8*ln2
    int n0 = blockIdx.x * 128;
    int bh = blockIdx.y;
    int b = bh >> 2, h = bh & 3;
    int sp = blockIdx.z;
    int kbase = sp * (NN / SPLIT);
    int tid = threadIdx.x;
    int w = tid >> 6, l = tid & 63, lr = l & 15, lh = l >> 4;

    __shared__ unsigned short Kl[2][64 * 72];
    __shared__ unsigned short Vl[2][64 * 72];
    __shared__ unsigned short Pl[4][32 * 72];

    const size_t qkBase = (size_t)b * NN * OO + h * HDD;
    const size_t vBase  = ((size_t)b * OO + h * HDD) * NN;

    const unsigned short* qrow0 = QT + qkBase + (size_t)(n0 + w * 32 + lr) * OO;
    const unsigned short* qrow1 = qrow0 + (size_t)16 * OO;
    bf16x8 qf00 = *(const bf16x8*)(qrow0 + 8 * lh);
    bf16x8 qf01 = *(const bf16x8*)(qrow0 + 32 + 8 * lh);
    bf16x8 qf10 = *(const bf16x8*)(qrow1 + 8 * lh);
    bf16x8 qf11 = *(const bf16x8*)(qrow1 + 32 + 8 * lh);

    int srow = tid >> 3;
    int scol = (tid & 7) * 8;
    const unsigned short* Kg = KT + qkBase + (size_t)(kbase + srow) * OO + scol;
    const unsigned short* Vg = Vb + vBase + (size_t)srow * NN + kbase + scol;
    int ldsW0 = srow * 72 + scol, ldsW1 = (srow + 32) * 72 + scol;

    bf16x8 ones;
#pragma unroll
    for (int j = 0; j < 8; ++j) ones[j] = (short)0x3F80;   // bf16 1.0

    f32x4 oacc[2][4] = {};
    f32x4 lacc[2] = {};
    float mrun0 = -1e30f, mrun1 = -1e30f;
    const f32x4 zero = {0.f, 0.f, 0.f, 0.f};
    unsigned short* plw = &Pl[w][0];

    {
        bf16x8 ka0 = *(const bf16x8*)Kg;
        bf16x8 ka1 = *(const bf16x8*)(Kg + (size_t)32 * OO);
        bf16x8 va0 = *(const bf16x8*)Vg;
        bf16x8 va1 = *(const bf16x8*)(Vg + (size_t)32 * NN);
        *(bf16x8*)&Kl[0][ldsW0] = ka0; *(bf16x8*)&Kl[0][ldsW1] = ka1;
        *(bf16x8*)&Vl[0][ldsW0] = va0; *(bf16x8*)&Vl[0][ldsW1] = va1;
    }
    __syncthreads();

    for (int t = 0; t < NT; ++t) {
        int cur = t & 1;
        bf16x8 ka0, ka1, va0, va1;
        if (t < NT - 1) {
            const unsigned short* kg = Kg + (size_t)(t + 1) * 64 * OO;
            const unsigned short* vg = Vg + (t + 1) * 64;
            ka0 = *(const bf16x8*)kg;
            ka1 = *(const bf16x8*)(kg + (size_t)32 * OO);
            va0 = *(const bf16x8*)vg;
            va1 = *(const bf16x8*)(vg + (size_t)32 * NN);
        }
        f32x4 S0[4], S1[4];
#pragma unroll
        for (int s = 0; s < 4; ++s) {
            const unsigned short* kb = &Kl[cur][(16 * s + lr) * 72 + 8 * lh];
            bf16x8 k0 = *(const bf16x8*)kb;
            bf16x8 k1 = *(const bf16x8*)(kb + 32);
            S0[s] = __builtin_amdgcn_mfma_f32_16x16x32_bf16(k0, qf00, zero, 0, 0, 0);
            S0[s] = __builtin_amdgcn_mfma_f32_16x16x32_bf16(k1, qf01, S0[s], 0, 0, 0);
            S1[s] = __builtin_amdgcn_mfma_f32_16x16x32_bf16(k0, qf10, zero, 0, 0, 0);
            S1[s] = __builtin_amdgcn_mfma_f32_16x16x32_bf16(k1, qf11, S1[s], 0, 0, 0);
        }
        {
            float tm = -1e30f;
#pragma unroll
            for (int s = 0; s < 4; ++s)
                tm = fmaxf(tm, fmaxf(fmaxf(S0[s][0], S0[s][1]), fmaxf(S0[s][2], S0[s][3])));
            tm = fmaxf(tm, __shfl_xor(tm, 16));
            tm = fmaxf(tm, __shfl_xor(tm, 32));
            if (__any(tm > mrun0 + THR)) {
                float mn = fmaxf(mrun0, tm);
                float sc = exp2f((mrun0 - mn) * L2E);
                lacc[0] *= sc;
#pragma unroll
                for (int dt = 0; dt < 4; ++dt) oacc[0][dt] *= sc;
                mrun0 = mn;
            }
            float mL = mrun0 * L2E;
#pragma unroll
            for (int s = 0; s < 4; ++s) {
                float p0 = exp2f(__builtin_fmaf(S0[s][0], L2E, -mL));
                float p1 = exp2f(__builtin_fmaf(S0[s][1], L2E, -mL));
                float p2 = exp2f(__builtin_fmaf(S0[s][2], L2E, -mL));
                float p3 = exp2f(__builtin_fmaf(S0[s][3], L2E, -mL));
                u32x2 v; v[0] = cvtpk(p0, p1); v[1] = cvtpk(p2, p3);
                *(u32x2*)(plw + lr * 72 + s * 16 + 4 * lh) = v;
            }
        }
        {
            float tm = -1e30f;
#pragma unroll
            for (int s = 0; s < 4; ++s)
                tm = fmaxf(tm, fmaxf(fmaxf(S1[s][0], S1[s][1]), fmaxf(S1[s][2], S1[s][3])));
            tm = fmaxf(tm, __shfl_xor(tm, 16));
            tm = fmaxf(tm, __shfl_xor(tm, 32));
            if (__any(tm > mrun1 + THR)) {
                float mn = fmaxf(mrun1, tm);
                float sc = exp2f((mrun1 - mn) * L2E);
                lacc[1] *= sc;
#pragma unroll
                for (int dt = 0; dt < 4; ++dt) oacc[1][dt] *= sc;
                mrun1 = mn;
            }
            float mL = mrun1 * L2E;
#pragma unroll
            for (int s = 0; s < 4; ++s) {
                float p0 = exp2f(__builtin_fmaf(S1[s][0], L2E, -mL));
                float p1 = exp2f(__builtin_fmaf(S1[s][1], L2E, -mL));
                float p2 = exp2f(__builtin_fmaf(S1[s][2], L2E, -mL));
                float p3 = exp2f(__builtin_fmaf(S1[s][3], L2E, -mL));
                u32x2 v; v[0] = cvtpk(p0, p1); v[1] = cvtpk(p2, p3);
                *(u32x2*)(plw + (16 + lr) * 72 + s * 16 + 4 * lh) = v;
            }
        }
#pragma unroll
        for (int c = 0; c < 2; ++c) {
            bf16x8 pf0 = *(const bf16x8*)(plw + lr * 72 + c * 32 + 8 * lh);
            bf16x8 pf1 = *(const bf16x8*)(plw + (16 + lr) * 72 + c * 32 + 8 * lh);
            lacc[0] = __builtin_amdgcn_mfma_f32_16x16x32_bf16(ones, pf0, lacc[0], 0, 0, 0);
            lacc[1] = __builtin_amdgcn_mfma_f32_16x16x32_bf16(ones, pf1, lacc[1], 0, 0, 0);
#pragma unroll
            for (int dt = 0; dt < 4; ++dt) {
                bf16x8 vf = *(const bf16x8*)&Vl[cur][(dt * 16 + lr) * 72 + c * 32 + 8 * lh];
                oacc[0][dt] = __builtin_amdgcn_mfma_f32_16x16x32_bf16(vf, pf0, oacc[0][dt], 0, 0, 0);
                oacc[1][dt] = __builtin_amdgcn_mfma_f32_16x16x32_bf16(vf, pf1, oacc[1][dt], 0, 0, 0);
            }
        }
        if (t < NT - 1) {
            int nxt = cur ^ 1;
            *(bf16x8*)&Kl[nxt][ldsW0] = ka0; *(bf16x8*)&Kl[nxt][ldsW1] = ka1;
            *(bf16x8*)&Vl[nxt][ldsW0] = va0; *(bf16x8*)&Vl[nxt][ldsW1] = va1;
        }
        __syncthreads();
    }

#pragma unroll
    for (int h2 = 0; h2 < 2; ++h2) {
        float mrun = h2 ? mrun1 : mrun0;
        float lrun = lacc[h2][0];
        int nrow = n0 + w * 32 + 16 * h2 + lr;
        if (SPLIT == 1) {
            float invL = 1.f / lrun;
            unsigned short* orow = AT + ((size_t)b * NN + nrow) * OO + h * HDD;
#pragma unroll
            for (int dt = 0; dt < 4; ++dt) {
                us4 res;
#pragma unroll
                for (int r = 0; r < 4; ++r) res[r] = f2b(oacc[h2][dt][r] * invL);
                *(us4*)(orow + dt * 16 + 4 * lh) = res;
            }
        } else {
            size_t rbase = ((size_t)(b * HH + h) * SPLIT + sp) * NN + nrow;
#pragma unroll
            for (int dt = 0; dt < 4; ++dt)
                *(f32x4*)(Opart + rbase * HDD + dt * 16 + 4 * lh) = oacc[h2][dt];
            if (lh == 0) { mlb[rbase * 2] = mrun; mlb[rbase * 2 + 1] = lrun; }
        }
    }
}

// ---------- kernel 3b: merge SPLIT KV-split partials ----------
template<int SPLIT>
__global__ void __launch_bounds__(256) k_amerge(const float* __restrict__ Opart,
                                                const float* __restrict__ mlb,
                                                unsigned short* __restrict__ AT) {
    int n0 = blockIdx.x * 64, bb = blockIdx.y;
    int h = threadIdx.x >> 6, l = threadIdx.x & 63;
    int n = n0 + l;
    size_t bs[SPLIT];
    float mv[SPLIT], lv[SPLIT], ev[SPLIT];
    float M = -1e30f;
#pragma unroll
    for (int s = 0; s < SPLIT; ++s) {
        bs[s] = ((size_t)(bb * HH + h) * SPLIT + s) * NN + n;
        mv[s] = mlb[bs[s] * 2]; lv[s] = mlb[bs[s] * 2 + 1];
        M = fmaxf(M, mv[s]);
    }
    float L = 0.f;
#pragma unroll
    for (int s = 0; s < SPLIT; ++s) { ev[s] = expf(mv[s] - M); L += lv[s] * ev[s]; }
    float invL = 1.f / L;
    unsigned short* orow = AT + ((size_t)(bb * NN + n)) * OO + h * HDD;
#pragma unroll
    for (int dt = 0; dt < 16; ++dt) {
        float acc[4] = {0.f, 0.f, 0.f, 0.f};
#pragma unroll
        for (int s = 0; s < SPLIT; ++s) {
            f32x4 a = *(const f32x4*)(Opart + bs[s] * HDD + 4 * dt);
#pragma unroll
            for (int r = 0; r < 4; ++r) acc[r] += a[r] * ev[s];
        }
        us4 o;
#pragma unroll
        for (int r = 0; r < 4; ++r) o[r] = f2b(acc[r] * invL);
        *(us4*)(orow + 4 * dt) = o;
    }
}

// ---------- kernel 4: fused MLP1+MLP2+gamma/point epilogue ----------
// Grid 256 blocks x 256 threads; block = 32 rows (b*N+n), X1 tile lives in LDS.
// Phase 1: X1l[32][256] = relu(AT*W1^T+b1). Phase 2: out = gamma*(X1l*W2^T+b2)+point.
__global__ void __launch_bounds__(256) k_mlp(
        const unsigned short* __restrict__ AT,
        const void* __restrict__ W1, const void* __restrict__ b1,
        const void* __restrict__ W2, const void* __restrict__ b2,
        const void* __restrict__ point,
        const void* __restrict__ gammaP,
        void* __restrict__ outP) {
    bool f32in = inIsF32(gammaP);
    float g = loadIn(gammaP, 0, f32in);
    __shared__ unsigned short X1l[32][264];   // stride 264hw = 132dw == 4 mod 32 -> 2-way max
    int tid = threadIdx.x, w = tid >> 6, l = tid & 63;
    int lr = l & 15, lh = l >> 4;
    int row0 = blockIdx.x * 32;               // global row (b*NN + n), 4096%32==0
    int colW = w * 64;

    // phase 1
    f32x4 acc1[2][4] = {};
    for (int k0 = 0; k0 < OO; k0 += 32) {
        bf16x8 af[2], bfr[4];
#pragma unroll
        for (int mi = 0; mi < 2; ++mi)
            af[mi] = *(const bf16x8*)(AT + (size_t)(row0 + mi * 16 + lr) * OO + k0 + 8 * lh);
#pragma unroll
        for (int ni = 0; ni < 4; ++ni)
            bfr[ni] = loadFrag(W1, (size_t)(colW + ni * 16 + lr) * OO + k0 + 8 * lh, f32in);
#pragma unroll
        for (int mi = 0; mi < 2; ++mi)
#pragma unroll
            for (int ni = 0; ni < 4; ++ni)
                acc1[mi][ni] = __builtin_amdgcn_mfma_f32_16x16x32_bf16(af[mi], bfr[ni], acc1[mi][ni], 0, 0, 0);
    }
#pragma unroll
    for (int mi = 0; mi < 2; ++mi)
#pragma unroll
        for (int ni = 0; ni < 4; ++ni) {
            int col = colW + ni * 16 + lr;
            float bia = loadIn(b1, col, f32in);
#pragma unroll
            for (int r = 0; r < 4; ++r) {
                float v = acc1[mi][ni][r] + bia;
                X1l[mi * 16 + lh * 4 + r][col] = f2b(fmaxf(v, 0.f));
            }
        }
    __syncthreads();

    // phase 2
    f32x4 acc2[2][4] = {};
    for (int k0 = 0; k0 < OO; k0 += 32) {
        bf16x8 af[2], bfr[4];
#pragma unroll
        for (int mi = 0; mi < 2; ++mi)
            af[mi] = *(const bf16x8*)&X1l[mi * 16 + lr][k0 + 8 * lh];
#pragma unroll
        for (int ni = 0; ni < 4; ++ni)
            bfr[ni] = loadFrag(W2, (size_t)(colW + ni * 16 + lr) * OO + k0 + 8 * lh, f32in);
#pragma unroll
        for (int mi = 0; mi < 2; ++mi)
#pragma unroll
            for (int ni = 0; ni < 4; ++ni)
                acc2[mi][ni] = __builtin_amdgcn_mfma_f32_16x16x32_bf16(af[mi], bfr[ni], acc2[mi][ni], 0, 0, 0);
    }
    int b = row0 >> 12;
#pragma unroll
    for (int mi = 0; mi < 2; ++mi)
#pragma unroll
        for (int ni = 0; ni < 4; ++ni) {
            int n = (row0 & (NN - 1)) + mi * 16 + lh * 4;
            int o = colW + ni * 16 + lr;
            size_t base = (size_t)b * OO * NN + (size_t)o * NN + n;
            float bia = loadIn(b2, o, f32in);
            if (f32in) {
                const f32x4 pv = *(const f32x4*)((const float*)point + base);
                f32x4 wv;
#pragma unroll
                for (int r = 0; r < 4; ++r) wv[r] = g * (acc2[mi][ni][r] + bia) + pv[r];
                *(f32x4*)((float*)outP + base) = wv;
            } else {
                const us4 pv = *(const us4*)((const unsigned short*)point + base);
                us4 wv;
#pragma unroll
                for (int r = 0; r < 4; ++r) wv[r] = f2b(g * (acc2[mi][ni][r] + bia) + b2f(pv[r]));
                *(us4*)((unsigned short*)outP + base) = wv;
            }
        }
}

extern "C" void kernel_launch(void* const* d_in, const int* in_sizes, int n_in,
                              void* d_out, int out_size, void* d_ws, size_t ws_size,
                              hipStream_t stream) {
    (void)in_sizes; (void)n_in; (void)out_size;
    const void* point = d_in[0];
    const void* text  = d_in[1];
    const void* Wt    = d_in[2];
    const void* bt    = d_in[3];
    const void* Wq    = d_in[4];
    const void* bq    = d_in[5];
    const void* Wk    = d_in[6];
    const void* bk    = d_in[7];
    const void* Wv    = d_in[8];
    const void* bv    = d_in[9];
    const void* W1    = d_in[10];
    const void* b1    = d_in[11];
    const void* W2    = d_in[12];
    const void* b2    = d_in[13];
    const void* gamma = d_in[14];

    char* ws = (char*)d_ws;
    const size_t SZ = (size_t)BB * NN * CC;   // 2 Mi bf16 = 4 MiB
    unsigned short* XTp = (unsigned short*)(ws + 4096);
    unsigned short* XTf = XTp + SZ;
    unsigned short* QT  = XTf + SZ;
    unsigned short* Vb  = QT + SZ;
    unsigned short* KT  = Vb + SZ;
    unsigned short* AT  = XTp;                // dead after k_qkv; NOT d_out (k_mlp fuses read+write)
    float* Opart = (float*)(KT + SZ);

    auto needFor = [&](int split) {
        return (size_t)4096 + 5 * SZ * 2
             + (size_t)BB * HH * split * NN * HDD * 4
             + (size_t)BB * HH * split * NN * 2 * 4;
    };

    k_tf<<<dim3(NN / 64, CC / 64, BB), 256, 0, stream>>>(point, text, Wt, bt, gamma, XTp, XTf);
    k_qkv<<<dim3(1536), 64, 0, stream>>>(XTp, XTf, Wq, bq, Wk, bk, Wv, bv, gamma, QT, KT, Vb);
    if (ws_size >= needFor(2)) {
        float* mlb = Opart + (size_t)BB * HH * 2 * NN * HDD;
        k_attn<2><<<dim3(NN / 128, BB * HH, 2), 256, 0, stream>>>(QT, KT, Vb, Opart, mlb, nullptr);
        k_amerge<2><<<dim3(NN / 64, BB), 256, 0, stream>>>(Opart, mlb, AT);
    } else {
        k_attn<1><<<dim3(NN / 128, BB * HH, 1), 256, 0, stream>>>(QT, KT, Vb, nullptr, nullptr, AT);
    }
    k_mlp<<<dim3(BB * NN / 32), 256, 0, stream>>>(AT, W1, b1, W2, b2, point, gamma, d_out);
}

// Round 13
// 128.881 us; speedup vs baseline: 1.5208x; 1.3080x over previous
//
#include <hip/hip_runtime.h>
#include <hip/hip_bf16.h>
#include <math.h>

#define BB   2
#define CC   256
#define NN   4096
#define DTXT 512
#define OO   256
#define HH   4
#define HDD  64

typedef __attribute__((ext_vector_type(4))) unsigned short us4;
typedef __attribute__((ext_vector_type(8))) short          bf16x8;
typedef __attribute__((ext_vector_type(4))) float          f32x4;
typedef __attribute__((ext_vector_type(2))) unsigned int   u32x2;

__device__ __forceinline__ float b2f(unsigned short u) {
    union { unsigned int i; float f; } x; x.i = ((unsigned int)u) << 16; return x.f;
}
__device__ __forceinline__ unsigned short f2b(float f) {
    union { float f; unsigned int i; } x; x.f = f;
    unsigned int r = (x.i + 0x7FFFu + ((x.i >> 16) & 1u)) >> 16;
    return (unsigned short)r;
}
__device__ __forceinline__ unsigned int cvtpk(float lo, float hi) {
    unsigned int r;
    asm volatile("v_cvt_pk_bf16_f32 %0, %1, %2" : "=v"(r) : "v"(lo), "v"(hi));
    return r;
}
__device__ __forceinline__ float loadIn(const void* p, size_t i, bool f32) {
    return f32 ? ((const float*)p)[i] : b2f(((const unsigned short*)p)[i]);
}
__device__ __forceinline__ bf16x8 loadFrag(const void* p, size_t off, bool f32) {
    if (!f32) return *(const bf16x8*)((const unsigned short*)p + off);
    const float* q = (const float*)p + off;
    f32x4 a = *(const f32x4*)q, b = *(const f32x4*)(q + 4);
    bf16x8 r;
    r[0] = (short)f2b(a[0]); r[1] = (short)f2b(a[1]);
    r[2] = (short)f2b(a[2]); r[3] = (short)f2b(a[3]);
    r[4] = (short)f2b(b[0]); r[5] = (short)f2b(b[1]);
    r[6] = (short)f2b(b[2]); r[7] = (short)f2b(b[3]);
    return r;
}
__device__ __forceinline__ bool inIsF32(const void* gammaP) {
    return ((const unsigned short*)gammaP)[0] == 0;
}
__device__ __forceinline__ unsigned short cvt1(const void* p, size_t i, bool f32) {
    return f32 ? f2b(((const float*)p)[i]) : ((const unsigned short*)p)[i];
}

// ---------- kernel 1: fused text-proj+GELU + transpose + weight-convert plane ----------
// grid (NN/64, CC/64, BB+1); z==BB converts Wq,Wk,Wv,W1,W2,biases -> bf16 in ws.
__global__ void __launch_bounds__(256) k_tf(const void* __restrict__ point,
                     const void* __restrict__ text,
                     const void* __restrict__ Wt,
                     const void* __restrict__ bt,
                     const void* __restrict__ gammaP,
                     const void* __restrict__ Wq, const void* __restrict__ bq,
                     const void* __restrict__ Wk, const void* __restrict__ bk,
                     const void* __restrict__ Wv, const void* __restrict__ bv,
                     const void* __restrict__ W1, const void* __restrict__ b1,
                     const void* __restrict__ W2, const void* __restrict__ b2,
                     unsigned short* __restrict__ wcvt,
                     unsigned short* __restrict__ xtp,
                     unsigned short* __restrict__ xtf) {
    bool f32in = inIsF32(gammaP);
    int tid = threadIdx.x;
    if (blockIdx.z == BB) {   // weight conversion plane (256 blocks)
        int id = blockIdx.y * 64 + blockIdx.x;
        int gid = id * 256 + tid;                 // 0..65535
        wcvt[gid]               = cvt1(Wq, gid, f32in);
        wcvt[65536 + gid]       = cvt1(Wk, gid, f32in);
        wcvt[131072 + gid]      = cvt1(Wv, gid, f32in);
        wcvt[196608 + gid]      = cvt1(W1, gid, f32in);
        wcvt[262144 + gid]      = cvt1(W2, gid, f32in);
        if (id == 0) {
            wcvt[327680 + tid] = cvt1(bq, tid, f32in);
            wcvt[327936 + tid] = cvt1(bk, tid, f32in);
            wcvt[328192 + tid] = cvt1(bv, tid, f32in);
            wcvt[328448 + tid] = cvt1(b1, tid, f32in);
            wcvt[328704 + tid] = cvt1(b2, tid, f32in);
        }
        return;
    }
    __shared__ float txt[DTXT];
    __shared__ float tv[64];
    __shared__ unsigned short tile[64][72];
    int b = blockIdx.z, c0 = blockIdx.y * 64, n0 = blockIdx.x * 64;
    int w = tid >> 6, l = tid & 63;

    for (int i = tid; i < DTXT; i += 256) txt[i] = loadIn(text, (size_t)b * DTXT + i, f32in);
    __syncthreads();
    {
        int c = c0 + w * 16 + (l >> 2);
        int q4 = (l & 3) * 128;
        float acc = 0.f;
        for (int it = 0; it < 128; it += 4) {
            int i = q4 + it;
            if (f32in) {
                f32x4 wv = *(const f32x4*)((const float*)Wt + (size_t)c * DTXT + i);
#pragma unroll
                for (int j = 0; j < 4; ++j) acc += wv[j] * txt[i + j];
            } else {
                us4 wv = *(const us4*)((const unsigned short*)Wt + (size_t)c * DTXT + i);
#pragma unroll
                for (int j = 0; j < 4; ++j) acc += b2f(wv[j]) * txt[i + j];
            }
        }
        acc += __shfl_xor(acc, 1);
        acc += __shfl_xor(acc, 2);
        if ((l & 3) == 0) {
            acc += loadIn(bt, c, f32in);
            tv[w * 16 + (l >> 2)] = 0.5f * acc * (1.f + erff(acc * 0.70710678118654752f));
        }
    }
#pragma unroll
    for (int it = 0; it < 2; ++it) {
        int cl = tid / 8 + it * 32;
        int nl = (tid % 8) * 8;
        size_t off = ((size_t)(b * CC + c0 + cl)) * NN + n0 + nl;
        unsigned short u[8];
        if (f32in) {
            const float* s = (const float*)point + off;
            f32x4 v0 = *(const f32x4*)s, v1 = *(const f32x4*)(s + 4);
#pragma unroll
            for (int j = 0; j < 4; ++j) { u[j] = f2b(v0[j]); u[4 + j] = f2b(v1[j]); }
        } else {
            const unsigned short* s = (const unsigned short*)point + off;
            us4 v0 = *(const us4*)s, v1 = *(const us4*)(s + 4);
#pragma unroll
            for (int j = 0; j < 4; ++j) { u[j] = v0[j]; u[4 + j] = v1[j]; }
        }
#pragma unroll
        for (int j = 0; j < 8; ++j) tile[cl][nl + j] = u[j];
    }
    __syncthreads();
#pragma unroll
    for (int it = 0; it < 2; ++it) {
        int nl = tid / 8 + it * 32;
        int cl = (tid % 8) * 8;
        size_t base = ((size_t)(b * NN + n0 + nl)) * CC + c0 + cl;
        us4 a0, a1, f0, f1;
#pragma unroll
        for (int j = 0; j < 4; ++j) {
            unsigned short u = tile[cl + j][nl];
            a0[j] = u; f0[j] = f2b(b2f(u) + tv[cl + j]);
        }
#pragma unroll
        for (int j = 0; j < 4; ++j) {
            unsigned short u = tile[cl + 4 + j][nl];
            a1[j] = u; f1[j] = f2b(b2f(u) + tv[cl + 4 + j]);
        }
        *(us4*)(xtp + base) = a0; *(us4*)(xtp + base + 4) = a1;
        *(us4*)(xtf + base) = f0; *(us4*)(xtf + base + 4) = f1;
    }
}

// ---------- one-wave 64x64 NT-GEMM tile body (bf16-only) ----------
__device__ __forceinline__ void gemm_tile64(
        const unsigned short* A, const unsigned short* Bm,
        const unsigned short* bias, bool biasRow, bool relu,
        int rowW, int colW, int K, int ldc,
        unsigned short* co, int l) {
    int lr = l & 15, lh = l >> 4;
    f32x4 acc[4][4] = {};
    for (int k0 = 0; k0 < K; k0 += 32) {
        bf16x8 af[4], bfr[4];
#pragma unroll
        for (int mi = 0; mi < 4; ++mi)
            af[mi] = *(const bf16x8*)(A + (size_t)(rowW + mi * 16 + lr) * K + k0 + 8 * lh);
#pragma unroll
        for (int ni = 0; ni < 4; ++ni)
            bfr[ni] = *(const bf16x8*)(Bm + (size_t)(colW + ni * 16 + lr) * K + k0 + 8 * lh);
#pragma unroll
        for (int mi = 0; mi < 4; ++mi)
#pragma unroll
            for (int ni = 0; ni < 4; ++ni)
                acc[mi][ni] = __builtin_amdgcn_mfma_f32_16x16x32_bf16(af[mi], bfr[ni], acc[mi][ni], 0, 0, 0);
    }
#pragma unroll
    for (int mi = 0; mi < 4; ++mi)
#pragma unroll
        for (int ni = 0; ni < 4; ++ni)
#pragma unroll
            for (int r = 0; r < 4; ++r) {
                int row = rowW + mi * 16 + lh * 4 + r;
                int col = colW + ni * 16 + lr;
                float v = acc[mi][ni][r] + b2f(bias[biasRow ? row : col]);
                if (relu) v = fmaxf(v, 0.f);
                co[(size_t)row * ldc + col] = f2b(v);
            }
}

// ---------- kernel 2: fused Q/K/V projections (bf16 ws weights) ----------
__global__ void __launch_bounds__(64) k_qkv(
        const unsigned short* __restrict__ XTp,
        const unsigned short* __restrict__ XTf,
        const unsigned short* __restrict__ wcvt,
        unsigned short* __restrict__ QT,
        unsigned short* __restrict__ KT,
        unsigned short* __restrict__ Vb) {
    const unsigned short* Wqb = wcvt;
    const unsigned short* Wkb = wcvt + 65536;
    const unsigned short* Wvb = wcvt + 131072;
    const unsigned short* bqb = wcvt + 327680;
    const unsigned short* bkb = wcvt + 327936;
    const unsigned short* bvb = wcvt + 328192;
    int bid = blockIdx.x, l = threadIdx.x;
    if (bid < 1024) {
        int t = bid & 511;
        bool isQ = bid < 512;
        int rowW = (t >> 2) * 64, colW = (t & 3) * 64;
        gemm_tile64(isQ ? XTp : XTf, isQ ? Wqb : Wkb,
                    isQ ? bqb : bkb, false, false,
                    rowW, colW, CC, OO, isQ ? QT : KT, l);
    } else {
        int t = bid - 1024;
        int b = t >> 8, r = t & 255;
        int rowW = (r & 3) * 64, colW = (r >> 2) * 64;
        gemm_tile64(Wvb, XTp + (size_t)b * NN * CC,
                    bvb, true, false,
                    rowW, colW, CC, NN, Vb + (size_t)b * OO * NN, l);
    }
}

// ---------- kernel 3: flash attention (R12/R10 proven config, UNTOUCHED) ----------
template<int SPLIT>
__global__ void __launch_bounds__(256) k_attn(const unsigned short* __restrict__ QT,
                                              const unsigned short* __restrict__ KT,
                                              const unsigned short* __restrict__ Vb,
                                              float* __restrict__ Opart,
                                              float* __restrict__ mlb,
                                              unsigned short* __restrict__ AT) {
    const int NT = NN / SPLIT / 64;
    const float L2E = 1.44269504088896f;
    const float THR = 5.54517744448f;          // 8*ln2
    int n0 = blockIdx.x * 128;
    int bh = blockIdx.y;
    int b = bh >> 2, h = bh & 3;
    int sp = blockIdx.z;
    int kbase = sp * (NN / SPLIT);
    int tid = threadIdx.x;
    int w = tid >> 6, l = tid & 63, lr = l & 15, lh = l >> 4;

    __shared__ unsigned short Kl[2][64 * 72];
    __shared__ unsigned short Vl[2][64 * 72];
    __shared__ unsigned short Pl[4][32 * 72];

    const size_t qkBase = (size_t)b * NN * OO + h * HDD;
    const size_t vBase  = ((size_t)b * OO + h * HDD) * NN;

    const unsigned short* qrow0 = QT + qkBase + (size_t)(n0 + w * 32 + lr) * OO;
    const unsigned short* qrow1 = qrow0 + (size_t)16 * OO;
    bf16x8 qf00 = *(const bf16x8*)(qrow0 + 8 * lh);
    bf16x8 qf01 = *(const bf16x8*)(qrow0 + 32 + 8 * lh);
    bf16x8 qf10 = *(const bf16x8*)(qrow1 + 8 * lh);
    bf16x8 qf11 = *(const bf16x8*)(qrow1 + 32 + 8 * lh);

    int srow = tid >> 3;
    int scol = (tid & 7) * 8;
    const unsigned short* Kg = KT + qkBase + (size_t)(kbase + srow) * OO + scol;
    const unsigned short* Vg = Vb + vBase + (size_t)srow * NN + kbase + scol;
    int ldsW0 = srow * 72 + scol, ldsW1 = (srow + 32) * 72 + scol;

    bf16x8 ones;
#pragma unroll
    for (int j = 0; j < 8; ++j) ones[j] = (short)0x3F80;

    f32x4 oacc[2][4] = {};
    f32x4 lacc[2] = {};
    float mrun0 = -1e30f, mrun1 = -1e30f;
    const f32x4 zero = {0.f, 0.f, 0.f, 0.f};
    unsigned short* plw = &Pl[w][0];

    {
        bf16x8 ka0 = *(const bf16x8*)Kg;
        bf16x8 ka1 = *(const bf16x8*)(Kg + (size_t)32 * OO);
        bf16x8 va0 = *(const bf16x8*)Vg;
        bf16x8 va1 = *(const bf16x8*)(Vg + (size_t)32 * NN);
        *(bf16x8*)&Kl[0][ldsW0] = ka0; *(bf16x8*)&Kl[0][ldsW1] = ka1;
        *(bf16x8*)&Vl[0][ldsW0] = va0; *(bf16x8*)&Vl[0][ldsW1] = va1;
    }
    __syncthreads();

    for (int t = 0; t < NT; ++t) {
        int cur = t & 1;
        bf16x8 ka0, ka1, va0, va1;
        if (t < NT - 1) {
            const unsigned short* kg = Kg + (size_t)(t + 1) * 64 * OO;
            const unsigned short* vg = Vg + (t + 1) * 64;
            ka0 = *(const bf16x8*)kg;
            ka1 = *(const bf16x8*)(kg + (size_t)32 * OO);
            va0 = *(const bf16x8*)vg;
            va1 = *(const bf16x8*)(vg + (size_t)32 * NN);
        }
        f32x4 S0[4], S1[4];
#pragma unroll
        for (int s = 0; s < 4; ++s) {
            const unsigned short* kb = &Kl[cur][(16 * s + lr) * 72 + 8 * lh];
            bf16x8 k0 = *(const bf16x8*)kb;
            bf16x8 k1 = *(const bf16x8*)(kb + 32);
            S0[s] = __builtin_amdgcn_mfma_f32_16x16x32_bf16(k0, qf00, zero, 0, 0, 0);
            S0[s] = __builtin_amdgcn_mfma_f32_16x16x32_bf16(k1, qf01, S0[s], 0, 0, 0);
            S1[s] = __builtin_amdgcn_mfma_f32_16x16x32_bf16(k0, qf10, zero, 0, 0, 0);
            S1[s] = __builtin_amdgcn_mfma_f32_16x16x32_bf16(k1, qf11, S1[s], 0, 0, 0);
        }
        {
            float tm = -1e30f;
#pragma unroll
            for (int s = 0; s < 4; ++s)
                tm = fmaxf(tm, fmaxf(fmaxf(S0[s][0], S0[s][1]), fmaxf(S0[s][2], S0[s][3])));
            tm = fmaxf(tm, __shfl_xor(tm, 16));
            tm = fmaxf(tm, __shfl_xor(tm, 32));
            if (__any(tm > mrun0 + THR)) {
                float mn = fmaxf(mrun0, tm);
                float sc = exp2f((mrun0 - mn) * L2E);
                lacc[0] *= sc;
#pragma unroll
                for (int dt = 0; dt < 4; ++dt) oacc[0][dt] *= sc;
                mrun0 = mn;
            }
            float mL = mrun0 * L2E;
#pragma unroll
            for (int s = 0; s < 4; ++s) {
                float p0 = exp2f(__builtin_fmaf(S0[s][0], L2E, -mL));
                float p1 = exp2f(__builtin_fmaf(S0[s][1], L2E, -mL));
                float p2 = exp2f(__builtin_fmaf(S0[s][2], L2E, -mL));
                float p3 = exp2f(__builtin_fmaf(S0[s][3], L2E, -mL));
                u32x2 v; v[0] = cvtpk(p0, p1); v[1] = cvtpk(p2, p3);
                *(u32x2*)(plw + lr * 72 + s * 16 + 4 * lh) = v;
            }
        }
        {
            float tm = -1e30f;
#pragma unroll
            for (int s = 0; s < 4; ++s)
                tm = fmaxf(tm, fmaxf(fmaxf(S1[s][0], S1[s][1]), fmaxf(S1[s][2], S1[s][3])));
            tm = fmaxf(tm, __shfl_xor(tm, 16));
            tm = fmaxf(tm, __shfl_xor(tm, 32));
            if (__any(tm > mrun1 + THR)) {
                float mn = fmaxf(mrun1, tm);
                float sc = exp2f((mrun1 - mn) * L2E);
                lacc[1] *= sc;
#pragma unroll
                for (int dt = 0; dt < 4; ++dt) oacc[1][dt] *= sc;
                mrun1 = mn;
            }
            float mL = mrun1 * L2E;
#pragma unroll
            for (int s = 0; s < 4; ++s) {
                float p0 = exp2f(__builtin_fmaf(S1[s][0], L2E, -mL));
                float p1 = exp2f(__builtin_fmaf(S1[s][1], L2E, -mL));
                float p2 = exp2f(__builtin_fmaf(S1[s][2], L2E, -mL));
                float p3 = exp2f(__builtin_fmaf(S1[s][3], L2E, -mL));
                u32x2 v; v[0] = cvtpk(p0, p1); v[1] = cvtpk(p2, p3);
                *(u32x2*)(plw + (16 + lr) * 72 + s * 16 + 4 * lh) = v;
            }
        }
#pragma unroll
        for (int c = 0; c < 2; ++c) {
            bf16x8 pf0 = *(const bf16x8*)(plw + lr * 72 + c * 32 + 8 * lh);
            bf16x8 pf1 = *(const bf16x8*)(plw + (16 + lr) * 72 + c * 32 + 8 * lh);
            lacc[0] = __builtin_amdgcn_mfma_f32_16x16x32_bf16(ones, pf0, lacc[0], 0, 0, 0);
            lacc[1] = __builtin_amdgcn_mfma_f32_16x16x32_bf16(ones, pf1, lacc[1], 0, 0, 0);
#pragma unroll
            for (int dt = 0; dt < 4; ++dt) {
                bf16x8 vf = *(const bf16x8*)&Vl[cur][(dt * 16 + lr) * 72 + c * 32 + 8 * lh];
                oacc[0][dt] = __builtin_amdgcn_mfma_f32_16x16x32_bf16(vf, pf0, oacc[0][dt], 0, 0, 0);
                oacc[1][dt] = __builtin_amdgcn_mfma_f32_16x16x32_bf16(vf, pf1, oacc[1][dt], 0, 0, 0);
            }
        }
        if (t < NT - 1) {
            int nxt = cur ^ 1;
            *(bf16x8*)&Kl[nxt][ldsW0] = ka0; *(bf16x8*)&Kl[nxt][ldsW1] = ka1;
            *(bf16x8*)&Vl[nxt][ldsW0] = va0; *(bf16x8*)&Vl[nxt][ldsW1] = va1;
        }
        __syncthreads();
    }

#pragma unroll
    for (int h2 = 0; h2 < 2; ++h2) {
        float mrun = h2 ? mrun1 : mrun0;
        float lrun = lacc[h2][0];
        int nrow = n0 + w * 32 + 16 * h2 + lr;
        if (SPLIT == 1) {
            float invL = 1.f / lrun;
            unsigned short* orow = AT + ((size_t)b * NN + nrow) * OO + h * HDD;
#pragma unroll
            for (int dt = 0; dt < 4; ++dt) {
                us4 res;
#pragma unroll
                for (int r = 0; r < 4; ++r) res[r] = f2b(oacc[h2][dt][r] * invL);
                *(us4*)(orow + dt * 16 + 4 * lh) = res;
            }
        } else {
            size_t rbase = ((size_t)(b * HH + h) * SPLIT + sp) * NN + nrow;
#pragma unroll
            for (int dt = 0; dt < 4; ++dt)
                *(f32x4*)(Opart + rbase * HDD + dt * 16 + 4 * lh) = oacc[h2][dt];
            if (lh == 0) { mlb[rbase * 2] = mrun; mlb[rbase * 2 + 1] = lrun; }
        }
    }
}

// ---------- kernel 4: fused [amerge +] MLP1 + MLP2 + gamma/point epilogue ----------
// SPLIT==2: phase 0 merges the 2 KV-split partials for this block's 32 rows into
// LDS X0l (read-once). SPLIT==1: phase 1 reads AT directly.
template<int SPLIT>
__global__ void __launch_bounds__(256) k_mlp(
        const unsigned short* __restrict__ AT,
        const float* __restrict__ Opart,
        const float* __restrict__ mlb,
        const unsigned short* __restrict__ wcvt,
        const void* __restrict__ point,
        const void* __restrict__ gammaP,
        void* __restrict__ outP) {
    const unsigned short* W1b = wcvt + 196608;
    const unsigned short* W2b = wcvt + 262144;
    const unsigned short* b1b = wcvt + 328448;
    const unsigned short* b2b = wcvt + 328704;
    bool f32in = inIsF32(gammaP);
    float g = loadIn(gammaP, 0, f32in);
    __shared__ unsigned short X0l[32][264];
    __shared__ unsigned short X1l[32][264];
    int tid = threadIdx.x, w = tid >> 6, l = tid & 63;
    int lr = l & 15, lh = l >> 4;
    int row0 = blockIdx.x * 32;               // global row (b*NN + n)
    int colW = w * 64;
    int b = row0 >> 12;

    if (SPLIT == 2) {
        // phase 0: merge partials -> X0l. thread = (row r=tid&31, 32-col chunk hb=tid>>5)
        int r = tid & 31, hb = tid >> 5;      // hb 0..7
        int h = hb >> 1;
        int d0 = (hb & 1) * 32;
        int n = (row0 & (NN - 1)) + r;
        size_t rb0 = (((size_t)(b * HH + h)) * 2 + 0) * NN + n;
        size_t rb1 = (((size_t)(b * HH + h)) * 2 + 1) * NN + n;
        float m0 = mlb[rb0 * 2], l0 = mlb[rb0 * 2 + 1];
        float m1 = mlb[rb1 * 2], l1 = mlb[rb1 * 2 + 1];
        float M = fmaxf(m0, m1);
        float e0 = expf(m0 - M), e1 = expf(m1 - M);
        float invL = 1.f / (l0 * e0 + l1 * e1);
        float c0 = e0 * invL, c1 = e1 * invL;
        const float* O0 = Opart + rb0 * HDD + d0;
        const float* O1 = Opart + rb1 * HDD + d0;
#pragma unroll
        for (int j = 0; j < 8; ++j) {
            f32x4 a = *(const f32x4*)(O0 + 4 * j);
            f32x4 c = *(const f32x4*)(O1 + 4 * j);
            float v0 = a[0] * c0 + c[0] * c1;
            float v1 = a[1] * c0 + c[1] * c1;
            float v2 = a[2] * c0 + c[2] * c1;
            float v3 = a[3] * c0 + c[3] * c1;
            u32x2 pk; pk[0] = cvtpk(v0, v1); pk[1] = cvtpk(v2, v3);
            *(u32x2*)&X0l[r][hb * 32 + 4 * j] = pk;
        }
        __syncthreads();
    }

    // phase 1: X1 = relu(X0 * W1^T + b1)
    f32x4 acc1[2][4] = {};
    for (int k0 = 0; k0 < OO; k0 += 32) {
        bf16x8 af[2], bfr[4];
#pragma unroll
        for (int mi = 0; mi < 2; ++mi) {
            if (SPLIT == 2)
                af[mi] = *(const bf16x8*)&X0l[mi * 16 + lr][k0 + 8 * lh];
            else
                af[mi] = *(const bf16x8*)(AT + (size_t)(row0 + mi * 16 + lr) * OO + k0 + 8 * lh);
        }
#pragma unroll
        for (int ni = 0; ni < 4; ++ni)
            bfr[ni] = *(const bf16x8*)(W1b + (size_t)(colW + ni * 16 + lr) * OO + k0 + 8 * lh);
#pragma unroll
        for (int mi = 0; mi < 2; ++mi)
#pragma unroll
            for (int ni = 0; ni < 4; ++ni)
                acc1[mi][ni] = __builtin_amdgcn_mfma_f32_16x16x32_bf16(af[mi], bfr[ni], acc1[mi][ni], 0, 0, 0);
    }
#pragma unroll
    for (int mi = 0; mi < 2; ++mi)
#pragma unroll
        for (int ni = 0; ni < 4; ++ni) {
            int col = colW + ni * 16 + lr;
            float bia = b2f(b1b[col]);
#pragma unroll
            for (int r = 0; r < 4; ++r) {
                float v = acc1[mi][ni][r] + bia;
                X1l[mi * 16 + lh * 4 + r][col] = f2b(fmaxf(v, 0.f));
            }
        }
    __syncthreads();

    // phase 2: out = gamma*(X1*W2^T + b2) + point  (transposed write)
    f32x4 acc2[2][4] = {};
    for (int k0 = 0; k0 < OO; k0 += 32) {
        bf16x8 af[2], bfr[4];
#pragma unroll
        for (int mi = 0; mi < 2; ++mi)
            af[mi] = *(const bf16x8*)&X1l[mi * 16 + lr][k0 + 8 * lh];
#pragma unroll
        for (int ni = 0; ni < 4; ++ni)
            bfr[ni] = *(const bf16x8*)(W2b + (size_t)(colW + ni * 16 + lr) * OO + k0 + 8 * lh);
#pragma unroll
        for (int mi = 0; mi < 2; ++mi)
#pragma unroll
            for (int ni = 0; ni < 4; ++ni)
                acc2[mi][ni] = __builtin_amdgcn_mfma_f32_16x16x32_bf16(af[mi], bfr[ni], acc2[mi][ni], 0, 0, 0);
    }
#pragma unroll
    for (int mi = 0; mi < 2; ++mi)
#pragma unroll
        for (int ni = 0; ni < 4; ++ni) {
            int n = (row0 & (NN - 1)) + mi * 16 + lh * 4;
            int o = colW + ni * 16 + lr;
            size_t base = (size_t)b * OO * NN + (size_t)o * NN + n;
            float bia = b2f(b2b[o]);
            if (f32in) {
                const f32x4 pv = *(const f32x4*)((const float*)point + base);
                f32x4 wv;
#pragma unroll
                for (int r = 0; r < 4; ++r) wv[r] = g * (acc2[mi][ni][r] + bia) + pv[r];
                *(f32x4*)((float*)outP + base) = wv;
            } else {
                const us4 pv = *(const us4*)((const unsigned short*)point + base);
                us4 wv;
#pragma unroll
                for (int r = 0; r < 4; ++r) wv[r] = f2b(g * (acc2[mi][ni][r] + bia) + b2f(pv[r]));
                *(us4*)((unsigned short*)outP + base) = wv;
            }
        }
}

extern "C" void kernel_launch(void* const* d_in, const int* in_sizes, int n_in,
                              void* d_out, int out_size, void* d_ws, size_t ws_size,
                              hipStream_t stream) {
    (void)in_sizes; (void)n_in; (void)out_size;
    const void* point = d_in[0];
    const void* text  = d_in[1];
    const void* Wt    = d_in[2];
    const void* bt    = d_in[3];
    const void* Wq    = d_in[4];
    const void* bq    = d_in[5];
    const void* Wk    = d_in[6];
    const void* bk    = d_in[7];
    const void* Wv    = d_in[8];
    const void* bv    = d_in[9];
    const void* W1    = d_in[10];
    const void* b1    = d_in[11];
    const void* W2    = d_in[12];
    const void* b2    = d_in[13];
    const void* gamma = d_in[14];

    char* ws = (char*)d_ws;
    const size_t SZ = (size_t)BB * NN * CC;   // 2 Mi bf16 = 4 MiB
    unsigned short* XTp  = (unsigned short*)(ws + 4096);
    unsigned short* XTf  = XTp + SZ;
    unsigned short* QT   = XTf + SZ;
    unsigned short* Vb   = QT + SZ;
    unsigned short* KT   = Vb + SZ;
    unsigned short* Wcvt = KT + SZ;           // 328,960 bf16 elems (~0.66 MB)
    float* Opart = (float*)(((uintptr_t)(Wcvt + 328960) + 255) & ~(uintptr_t)255);
    float* mlb   = Opart + (size_t)BB * HH * 2 * NN * HDD;
    unsigned short* AT = XTp;                 // SPLIT=1 fallback scratch (dead after k_qkv)

    size_t need2 = (size_t)((char*)(mlb + (size_t)BB * HH * 2 * NN * 2) - ws);
    bool split2 = ws_size >= need2;

    k_tf<<<dim3(NN / 64, CC / 64, BB + 1), 256, 0, stream>>>(
        point, text, Wt, bt, gamma, Wq, bq, Wk, bk, Wv, bv, W1, b1, W2, b2,
        Wcvt, XTp, XTf);
    k_qkv<<<dim3(1536), 64, 0, stream>>>(XTp, XTf, Wcvt, QT, KT, Vb);
    if (split2) {
        k_attn<2><<<dim3(NN / 128, BB * HH, 2), 256, 0, stream>>>(QT, KT, Vb, Opart, mlb, nullptr);
        k_mlp<2><<<dim3(BB * NN / 32), 256, 0, stream>>>(nullptr, Opart, mlb, Wcvt, point, gamma, d_out);
    } else {
        k_attn<1><<<dim3(NN / 128, BB * HH, 1), 256, 0, stream>>>(QT, KT, Vb, nullptr, nullptr, AT);
        k_mlp<1><<<dim3(BB * NN / 32), 256, 0, stream>>>(AT, nullptr, nullptr, Wcvt, point, gamma, d_out);
    }
}

// Round 15
// 128.686 us; speedup vs baseline: 1.5231x; 1.0015x over previous
//
#include <hip/hip_runtime.h>
#include <hip/hip_bf16.h>
#include <math.h>

#define BB   2
#define CC   256
#define NN   4096
#define DTXT 512
#define OO   256
#define HH   4
#define HDD  64

typedef __attribute__((ext_vector_type(4))) unsigned short us4;
typedef __attribute__((ext_vector_type(8))) short          bf16x8;
typedef __attribute__((ext_vector_type(4))) float          f32x4;
typedef __attribute__((ext_vector_type(2))) unsigned int   u32x2;

__device__ __forceinline__ float b2f(unsigned short u) {
    union { unsigned int i; float f; } x; x.i = ((unsigned int)u) << 16; return x.f;
}
__device__ __forceinline__ unsigned short f2b(float f) {
    union { float f; unsigned int i; } x; x.f = f;
    unsigned int r = (x.i + 0x7FFFu + ((x.i >> 16) & 1u)) >> 16;
    return (unsigned short)r;
}
__device__ __forceinline__ unsigned int cvtpk(float lo, float hi) {
    unsigned int r;
    asm volatile("v_cvt_pk_bf16_f32 %0, %1, %2" : "=v"(r) : "v"(lo), "v"(hi));
    return r;
}
__device__ __forceinline__ float loadIn(const void* p, size_t i, bool f32) {
    return f32 ? ((const float*)p)[i] : b2f(((const unsigned short*)p)[i]);
}
__device__ __forceinline__ bool inIsF32(const void* gammaP) {
    return ((const unsigned short*)gammaP)[0] == 0;
}
__device__ __forceinline__ unsigned short cvt1(const void* p, size_t i, bool f32) {
    return f32 ? f2b(((const float*)p)[i]) : ((const unsigned short*)p)[i];
}

// ---------- kernel 1: fused text-proj+GELU + transpose + weight-convert plane ----------
__global__ void __launch_bounds__(256) k_tf(const void* __restrict__ point,
                     const void* __restrict__ text,
                     const void* __restrict__ Wt,
                     const void* __restrict__ bt,
                     const void* __restrict__ gammaP,
                     const void* __restrict__ Wq, const void* __restrict__ bq,
                     const void* __restrict__ Wk, const void* __restrict__ bk,
                     const void* __restrict__ Wv, const void* __restrict__ bv,
                     const void* __restrict__ W1, const void* __restrict__ b1,
                     const void* __restrict__ W2, const void* __restrict__ b2,
                     unsigned short* __restrict__ wcvt,
                     unsigned short* __restrict__ xtp,
                     unsigned short* __restrict__ xtf) {
    bool f32in = inIsF32(gammaP);
    int tid = threadIdx.x;
    if (blockIdx.z == BB) {   // weight conversion plane (256 blocks)
        int id = blockIdx.y * 64 + blockIdx.x;
        int gid = id * 256 + tid;                 // 0..65535
        wcvt[gid]               = cvt1(Wq, gid, f32in);
        wcvt[65536 + gid]       = cvt1(Wk, gid, f32in);
        wcvt[131072 + gid]      = cvt1(Wv, gid, f32in);
        wcvt[196608 + gid]      = cvt1(W1, gid, f32in);
        wcvt[262144 + gid]      = cvt1(W2, gid, f32in);
        if (id == 0) {
            wcvt[327680 + tid] = cvt1(bq, tid, f32in);
            wcvt[327936 + tid] = cvt1(bk, tid, f32in);
            wcvt[328192 + tid] = cvt1(bv, tid, f32in);
            wcvt[328448 + tid] = cvt1(b1, tid, f32in);
            wcvt[328704 + tid] = cvt1(b2, tid, f32in);
        }
        return;
    }
    __shared__ float txt[DTXT];
    __shared__ float tv[64];
    __shared__ unsigned short tile[64][72];
    int b = blockIdx.z, c0 = blockIdx.y * 64, n0 = blockIdx.x * 64;
    int w = tid >> 6, l = tid & 63;

    for (int i = tid; i < DTXT; i += 256) txt[i] = loadIn(text, (size_t)b * DTXT + i, f32in);
    __syncthreads();
    {
        int c = c0 + w * 16 + (l >> 2);
        int q4 = (l & 3) * 128;
        float acc = 0.f;
        for (int it = 0; it < 128; it += 4) {
            int i = q4 + it;
            if (f32in) {
                f32x4 wv = *(const f32x4*)((const float*)Wt + (size_t)c * DTXT + i);
#pragma unroll
                for (int j = 0; j < 4; ++j) acc += wv[j] * txt[i + j];
            } else {
                us4 wv = *(const us4*)((const unsigned short*)Wt + (size_t)c * DTXT + i);
#pragma unroll
                for (int j = 0; j < 4; ++j) acc += b2f(wv[j]) * txt[i + j];
            }
        }
        acc += __shfl_xor(acc, 1);
        acc += __shfl_xor(acc, 2);
        if ((l & 3) == 0) {
            acc += loadIn(bt, c, f32in);
            tv[w * 16 + (l >> 2)] = 0.5f * acc * (1.f + erff(acc * 0.70710678118654752f));
        }
    }
#pragma unroll
    for (int it = 0; it < 2; ++it) {
        int cl = tid / 8 + it * 32;
        int nl = (tid % 8) * 8;
        size_t off = ((size_t)(b * CC + c0 + cl)) * NN + n0 + nl;
        unsigned short u[8];
        if (f32in) {
            const float* s = (const float*)point + off;
            f32x4 v0 = *(const f32x4*)s, v1 = *(const f32x4*)(s + 4);
#pragma unroll
            for (int j = 0; j < 4; ++j) { u[j] = f2b(v0[j]); u[4 + j] = f2b(v1[j]); }
        } else {
            const unsigned short* s = (const unsigned short*)point + off;
            us4 v0 = *(const us4*)s, v1 = *(const us4*)(s + 4);
#pragma unroll
            for (int j = 0; j < 4; ++j) { u[j] = v0[j]; u[4 + j] = v1[j]; }
        }
#pragma unroll
        for (int j = 0; j < 8; ++j) tile[cl][nl + j] = u[j];
    }
    __syncthreads();
#pragma unroll
    for (int it = 0; it < 2; ++it) {
        int nl = tid / 8 + it * 32;
        int cl = (tid % 8) * 8;
        size_t base = ((size_t)(b * NN + n0 + nl)) * CC + c0 + cl;
        us4 a0, a1, f0, f1;
#pragma unroll
        for (int j = 0; j < 4; ++j) {
            unsigned short u = tile[cl + j][nl];
            a0[j] = u; f0[j] = f2b(b2f(u) + tv[cl + j]);
        }
#pragma unroll
        for (int j = 0; j < 4; ++j) {
            unsigned short u = tile[cl + 4 + j][nl];
            a1[j] = u; f1[j] = f2b(b2f(u) + tv[cl + 4 + j]);
        }
        *(us4*)(xtp + base) = a0; *(us4*)(xtp + base + 4) = a1;
        *(us4*)(xtf + base) = f0; *(us4*)(xtf + base + 4) = f1;
    }
}

// ---------- one-wave 64x64 NT-GEMM tile body (bf16-only) ----------
__device__ __forceinline__ void gemm_tile64(
        const unsigned short* A, const unsigned short* Bm,
        const unsigned short* bias, bool biasRow, bool relu,
        int rowW, int colW, int K, int ldc,
        unsigned short* co, int l) {
    int lr = l & 15, lh = l >> 4;
    f32x4 acc[4][4] = {};
    for (int k0 = 0; k0 < K; k0 += 32) {
        bf16x8 af[4], bfr[4];
#pragma unroll
        for (int mi = 0; mi < 4; ++mi)
            af[mi] = *(const bf16x8*)(A + (size_t)(rowW + mi * 16 + lr) * K + k0 + 8 * lh);
#pragma unroll
        for (int ni = 0; ni < 4; ++ni)
            bfr[ni] = *(const bf16x8*)(Bm + (size_t)(colW + ni * 16 + lr) * K + k0 + 8 * lh);
#pragma unroll
        for (int mi = 0; mi < 4; ++mi)
#pragma unroll
            for (int ni = 0; ni < 4; ++ni)
                acc[mi][ni] = __builtin_amdgcn_mfma_f32_16x16x32_bf16(af[mi], bfr[ni], acc[mi][ni], 0, 0, 0);
    }
#pragma unroll
    for (int mi = 0; mi < 4; ++mi)
#pragma unroll
        for (int ni = 0; ni < 4; ++ni)
#pragma unroll
            for (int r = 0; r < 4; ++r) {
                int row = rowW + mi * 16 + lh * 4 + r;
                int col = colW + ni * 16 + lr;
                float v = acc[mi][ni][r] + b2f(bias[biasRow ? row : col]);
                if (relu) v = fmaxf(v, 0.f);
                co[(size_t)row * ldc + col] = f2b(v);
            }
}

// ---------- kernel 2: fused Q/K/V projections (bf16 ws weights) ----------
__global__ void __launch_bounds__(64) k_qkv(
        const unsigned short* __restrict__ XTp,
        const unsigned short* __restrict__ XTf,
        const unsigned short* __restrict__ wcvt,
        unsigned short* __restrict__ QT,
        unsigned short* __restrict__ KT,
        unsigned short* __restrict__ Vb) {
    const unsigned short* Wqb = wcvt;
    const unsigned short* Wkb = wcvt + 65536;
    const unsigned short* Wvb = wcvt + 131072;
    const unsigned short* bqb = wcvt + 327680;
    const unsigned short* bkb = wcvt + 327936;
    const unsigned short* bvb = wcvt + 328192;
    int bid = blockIdx.x, l = threadIdx.x;
    if (bid < 1024) {
        int t = bid & 511;
        bool isQ = bid < 512;
        int rowW = (t >> 2) * 64, colW = (t & 3) * 64;
        gemm_tile64(isQ ? XTp : XTf, isQ ? Wqb : Wkb,
                    isQ ? bqb : bkb, false, false,
                    rowW, colW, CC, OO, isQ ? QT : KT, l);
    } else {
        int t = bid - 1024;
        int b = t >> 8, r = t & 255;
        int rowW = (r & 3) * 64, colW = (r >> 2) * 64;
        gemm_tile64(Wvb, XTp + (size_t)b * NN * CC,
                    bvb, true, false,
                    rowW, colW, CC, NN, Vb + (size_t)b * OO * NN, l);
    }
}

// ---------- kernel 3: flash attention (R13-passed config, byte-exact revert) ----------
template<int SPLIT>
__global__ void __launch_bounds__(256) k_attn(const unsigned short* __restrict__ QT,
                                              const unsigned short* __restrict__ KT,
                                              const unsigned short* __restrict__ Vb,
                                              float* __restrict__ Opart,
                                              float* __restrict__ mlb,
                                              unsigned short* __restrict__ AT) {
    const int NT = NN / SPLIT / 64;
    const float L2E = 1.44269504088896f;
    const float THR = 5.54517744448f;          // 8*ln2
    int n0 = blockIdx.x * 128;
    int bh = blockIdx.y;
    int b = bh >> 2, h = bh & 3;
    int sp = blockIdx.z;
    int kbase = sp * (NN / SPLIT);
    int tid = threadIdx.x;
    int w = tid >> 6, l = tid & 63, lr = l & 15, lh = l >> 4;

    __shared__ unsigned short Kl[2][64 * 72];
    __shared__ unsigned short Vl[2][64 * 72];
    __shared__ unsigned short Pl[4][32 * 72];

    const size_t qkBase = (size_t)b * NN * OO + h * HDD;
    const size_t vBase  = ((size_t)b * OO + h * HDD) * NN;

    const unsigned short* qrow0 = QT + qkBase + (size_t)(n0 + w * 32 + lr) * OO;
    const unsigned short* qrow1 = qrow0 + (size_t)16 * OO;
    bf16x8 qf00 = *(const bf16x8*)(qrow0 + 8 * lh);
    bf16x8 qf01 = *(const bf16x8*)(qrow0 + 32 + 8 * lh);
    bf16x8 qf10 = *(const bf16x8*)(qrow1 + 8 * lh);
    bf16x8 qf11 = *(const bf16x8*)(qrow1 + 32 + 8 * lh);

    int srow = tid >> 3;
    int scol = (tid & 7) * 8;
    const unsigned short* Kg = KT + qkBase + (size_t)(kbase + srow) * OO + scol;
    const unsigned short* Vg = Vb + vBase + (size_t)srow * NN + kbase + scol;
    int ldsW0 = srow * 72 + scol, ldsW1 = (srow + 32) * 72 + scol;

    bf16x8 ones;
#pragma unroll
    for (int j = 0; j < 8; ++j) ones[j] = (short)0x3F80;

    f32x4 oacc[2][4] = {};
    f32x4 lacc[2] = {};
    float mrun0 = -1e30f, mrun1 = -1e30f;
    const f32x4 zero = {0.f, 0.f, 0.f, 0.f};
    unsigned short* plw = &Pl[w][0];

    {
        bf16x8 ka0 = *(const bf16x8*)Kg;
        bf16x8 ka1 = *(const bf16x8*)(Kg + (size_t)32 * OO);
        bf16x8 va0 = *(const bf16x8*)Vg;
        bf16x8 va1 = *(const bf16x8*)(Vg + (size_t)32 * NN);
        *(bf16x8*)&Kl[0][ldsW0] = ka0; *(bf16x8*)&Kl[0][ldsW1] = ka1;
        *(bf16x8*)&Vl[0][ldsW0] = va0; *(bf16x8*)&Vl[0][ldsW1] = va1;
    }
    __syncthreads();

    for (int t = 0; t < NT; ++t) {
        int cur = t & 1;
        bf16x8 ka0, ka1, va0, va1;
        if (t < NT - 1) {
            const unsigned short* kg = Kg + (size_t)(t + 1) * 64 * OO;
            const unsigned short* vg = Vg + (t + 1) * 64;
            ka0 = *(const bf16x8*)kg;
            ka1 = *(const bf16x8*)(kg + (size_t)32 * OO);
            va0 = *(const bf16x8*)vg;
            va1 = *(const bf16x8*)(vg + (size_t)32 * NN);
        }
        f32x4 S0[4], S1[4];
#pragma unroll
        for (int s = 0; s < 4; ++s) {
            const unsigned short* kb = &Kl[cur][(16 * s + lr) * 72 + 8 * lh];
            bf16x8 k0 = *(const bf16x8*)kb;
            bf16x8 k1 = *(const bf16x8*)(kb + 32);
            S0[s] = __builtin_amdgcn_mfma_f32_16x16x32_bf16(k0, qf00, zero, 0, 0, 0);
            S0[s] = __builtin_amdgcn_mfma_f32_16x16x32_bf16(k1, qf01, S0[s], 0, 0, 0);
            S1[s] = __builtin_amdgcn_mfma_f32_16x16x32_bf16(k0, qf10, zero, 0, 0, 0);
            S1[s] = __builtin_amdgcn_mfma_f32_16x16x32_bf16(k1, qf11, S1[s], 0, 0, 0);
        }
        {
            float tm = -1e30f;
#pragma unroll
            for (int s = 0; s < 4; ++s)
                tm = fmaxf(tm, fmaxf(fmaxf(S0[s][0], S0[s][1]), fmaxf(S0[s][2], S0[s][3])));
            tm = fmaxf(tm, __shfl_xor(tm, 16));
            tm = fmaxf(tm, __shfl_xor(tm, 32));
            if (__any(tm > mrun0 + THR)) {
                float mn = fmaxf(mrun0, tm);
                float sc = exp2f((mrun0 - mn) * L2E);
                lacc[0] *= sc;
#pragma unroll
                for (int dt = 0; dt < 4; ++dt) oacc[0][dt] *= sc;
                mrun0 = mn;
            }
            float mL = mrun0 * L2E;
#pragma unroll
            for (int s = 0; s < 4; ++s) {
                float p0 = exp2f(__builtin_fmaf(S0[s][0], L2E, -mL));
                float p1 = exp2f(__builtin_fmaf(S0[s][1], L2E, -mL));
                float p2 = exp2f(__builtin_fmaf(S0[s][2], L2E, -mL));
                float p3 = exp2f(__builtin_fmaf(S0[s][3], L2E, -mL));
                u32x2 v; v[0] = cvtpk(p0, p1); v[1] = cvtpk(p2, p3);
                *(u32x2*)(plw + lr * 72 + s * 16 + 4 * lh) = v;
            }
        }
        {
            float tm = -1e30f;
#pragma unroll
            for (int s = 0; s < 4; ++s)
                tm = fmaxf(tm, fmaxf(fmaxf(S1[s][0], S1[s][1]), fmaxf(S1[s][2], S1[s][3])));
            tm = fmaxf(tm, __shfl_xor(tm, 16));
            tm = fmaxf(tm, __shfl_xor(tm, 32));
            if (__any(tm > mrun1 + THR)) {
                float mn = fmaxf(mrun1, tm);
                float sc = exp2f((mrun1 - mn) * L2E);
                lacc[1] *= sc;
#pragma unroll
                for (int dt = 0; dt < 4; ++dt) oacc[1][dt] *= sc;
                mrun1 = mn;
            }
            float mL = mrun1 * L2E;
#pragma unroll
            for (int s = 0; s < 4; ++s) {
                float p0 = exp2f(__builtin_fmaf(S1[s][0], L2E, -mL));
                float p1 = exp2f(__builtin_fmaf(S1[s][1], L2E, -mL));
                float p2 = exp2f(__builtin_fmaf(S1[s][2], L2E, -mL));
                float p3 = exp2f(__builtin_fmaf(S1[s][3], L2E, -mL));
                u32x2 v; v[0] = cvtpk(p0, p1); v[1] = cvtpk(p2, p3);
                *(u32x2*)(plw + (16 + lr) * 72 + s * 16 + 4 * lh) = v;
            }
        }
#pragma unroll
        for (int c = 0; c < 2; ++c) {
            bf16x8 pf0 = *(const bf16x8*)(plw + lr * 72 + c * 32 + 8 * lh);
            bf16x8 pf1 = *(const bf16x8*)(plw + (16 + lr) * 72 + c * 32 + 8 * lh);
            lacc[0] = __builtin_amdgcn_mfma_f32_16x16x32_bf16(ones, pf0, lacc[0], 0, 0, 0);
            lacc[1] = __builtin_amdgcn_mfma_f32_16x16x32_bf16(ones, pf1, lacc[1], 0, 0, 0);
#pragma unroll
            for (int dt = 0; dt < 4; ++dt) {
                bf16x8 vf = *(const bf16x8*)&Vl[cur][(dt * 16 + lr) * 72 + c * 32 + 8 * lh];
                oacc[0][dt] = __builtin_amdgcn_mfma_f32_16x16x32_bf16(vf, pf0, oacc[0][dt], 0, 0, 0);
                oacc[1][dt] = __builtin_amdgcn_mfma_f32_16x16x32_bf16(vf, pf1, oacc[1][dt], 0, 0, 0);
            }
        }
        if (t < NT - 1) {
            int nxt = cur ^ 1;
            *(bf16x8*)&Kl[nxt][ldsW0] = ka0; *(bf16x8*)&Kl[nxt][ldsW1] = ka1;
            *(bf16x8*)&Vl[nxt][ldsW0] = va0; *(bf16x8*)&Vl[nxt][ldsW1] = va1;
        }
        __syncthreads();
    }

#pragma unroll
    for (int h2 = 0; h2 < 2; ++h2) {
        float mrun = h2 ? mrun1 : mrun0;
        float lrun = lacc[h2][0];
        int nrow = n0 + w * 32 + 16 * h2 + lr;
        if (SPLIT == 1) {
            float invL = 1.f / lrun;
            unsigned short* orow = AT + ((size_t)b * NN + nrow) * OO + h * HDD;
#pragma unroll
            for (int dt = 0; dt < 4; ++dt) {
                us4 res;
#pragma unroll
                for (int r = 0; r < 4; ++r) res[r] = f2b(oacc[h2][dt][r] * invL);
                *(us4*)(orow + dt * 16 + 4 * lh) = res;
            }
        } else {
            size_t rbase = ((size_t)(b * HH + h) * SPLIT + sp) * NN + nrow;
#pragma unroll
            for (int dt = 0; dt < 4; ++dt)
                *(f32x4*)(Opart + rbase * HDD + dt * 16 + 4 * lh) = oacc[h2][dt];
            if (lh == 0) { mlb[rbase * 2] = mrun; mlb[rbase * 2 + 1] = lrun; }
        }
    }
}

// ---------- kernel 4: fused [amerge +] MLP1 + MLP2 + gamma/point epilogue ----------
template<int SPLIT>
__global__ void __launch_bounds__(256) k_mlp(
        const unsigned short* __restrict__ AT,
        const float* __restrict__ Opart,
        const float* __restrict__ mlb,
        const unsigned short* __restrict__ wcvt,
        const void* __restrict__ point,
        const void* __restrict__ gammaP,
        void* __restrict__ outP) {
    const unsigned short* W1b = wcvt + 196608;
    const unsigned short* W2b = wcvt + 262144;
    const unsigned short* b1b = wcvt + 328448;
    const unsigned short* b2b = wcvt + 328704;
    bool f32in = inIsF32(gammaP);
    float g = loadIn(gammaP, 0, f32in);
    __shared__ unsigned short X0l[32][264];
    __shared__ unsigned short X1l[32][264];
    int tid = threadIdx.x, w = tid >> 6, l = tid & 63;
    int lr = l & 15, lh = l >> 4;
    int row0 = blockIdx.x * 32;               // global row (b*NN + n)
    int colW = w * 64;
    int b = row0 >> 12;

    if (SPLIT == 2) {
        int r = tid & 31, hb = tid >> 5;      // hb 0..7
        int h = hb >> 1;
        int d0 = (hb & 1) * 32;
        int n = (row0 & (NN - 1)) + r;
        size_t rb0 = (((size_t)(b * HH + h)) * 2 + 0) * NN + n;
        size_t rb1 = (((size_t)(b * HH + h)) * 2 + 1) * NN + n;
        float m0 = mlb[rb0 * 2], l0 = mlb[rb0 * 2 + 1];
        float m1 = mlb[rb1 * 2], l1 = mlb[rb1 * 2 + 1];
        float M = fmaxf(m0, m1);
        float e0 = expf(m0 - M), e1 = expf(m1 - M);
        float invL = 1.f / (l0 * e0 + l1 * e1);
        float c0 = e0 * invL, c1 = e1 * invL;
        const float* O0 = Opart + rb0 * HDD + d0;
        const float* O1 = Opart + rb1 * HDD + d0;
#pragma unroll
        for (int j = 0; j < 8; ++j) {
            f32x4 a = *(const f32x4*)(O0 + 4 * j);
            f32x4 c = *(const f32x4*)(O1 + 4 * j);
            float v0 = a[0] * c0 + c[0] * c1;
            float v1 = a[1] * c0 + c[1] * c1;
            float v2 = a[2] * c0 + c[2] * c1;
            float v3 = a[3] * c0 + c[3] * c1;
            u32x2 pk; pk[0] = cvtpk(v0, v1); pk[1] = cvtpk(v2, v3);
            *(u32x2*)&X0l[r][hb * 32 + 4 * j] = pk;
        }
        __syncthreads();
    }

    // phase 1: X1 = relu(X0 * W1^T + b1)
    f32x4 acc1[2][4] = {};
    for (int k0 = 0; k0 < OO; k0 += 32) {
        bf16x8 af[2], bfr[4];
#pragma unroll
        for (int mi = 0; mi < 2; ++mi) {
            if (SPLIT == 2)
                af[mi] = *(const bf16x8*)&X0l[mi * 16 + lr][k0 + 8 * lh];
            else
                af[mi] = *(const bf16x8*)(AT + (size_t)(row0 + mi * 16 + lr) * OO + k0 + 8 * lh);
        }
#pragma unroll
        for (int ni = 0; ni < 4; ++ni)
            bfr[ni] = *(const bf16x8*)(W1b + (size_t)(colW + ni * 16 + lr) * OO + k0 + 8 * lh);
#pragma unroll
        for (int mi = 0; mi < 2; ++mi)
#pragma unroll
            for (int ni = 0; ni < 4; ++ni)
                acc1[mi][ni] = __builtin_amdgcn_mfma_f32_16x16x32_bf16(af[mi], bfr[ni], acc1[mi][ni], 0, 0, 0);
    }
#pragma unroll
    for (int mi = 0; mi < 2; ++mi)
#pragma unroll
        for (int ni = 0; ni < 4; ++ni) {
            int col = colW + ni * 16 + lr;
            float bia = b2f(b1b[col]);
#pragma unroll
            for (int r = 0; r < 4; ++r) {
                float v = acc1[mi][ni][r] + bia;
                X1l[mi * 16 + lh * 4 + r][col] = f2b(fmaxf(v, 0.f));
            }
        }
    __syncthreads();

    // phase 2: out = gamma*(X1*W2^T + b2) + point  (transposed write)
    f32x4 acc2[2][4] = {};
    for (int k0 = 0; k0 < OO; k0 += 32) {
        bf16x8 af[2], bfr[4];
#pragma unroll
        for (int mi = 0; mi < 2; ++mi)
            af[mi] = *(const bf16x8*)&X1l[mi * 16 + lr][k0 + 8 * lh];
#pragma unroll
        for (int ni = 0; ni < 4; ++ni)
            bfr[ni] = *(const bf16x8*)(W2b + (size_t)(colW + ni * 16 + lr) * OO + k0 + 8 * lh);
#pragma unroll
        for (int mi = 0; mi < 2; ++mi)
#pragma unroll
            for (int ni = 0; ni < 4; ++ni)
                acc2[mi][ni] = __builtin_amdgcn_mfma_f32_16x16x32_bf16(af[mi], bfr[ni], acc2[mi][ni], 0, 0, 0);
    }
#pragma unroll
    for (int mi = 0; mi < 2; ++mi)
#pragma unroll
        for (int ni = 0; ni < 4; ++ni) {
            int n = (row0 & (NN - 1)) + mi * 16 + lh * 4;
            int o = colW + ni * 16 + lr;
            size_t base = (size_t)b * OO * NN + (size_t)o * NN + n;
            float bia = b2f(b2b[o]);
            if (f32in) {
                const f32x4 pv = *(const f32x4*)((const float*)point + base);
                f32x4 wv;
#pragma unroll
                for (int r = 0; r < 4; ++r) wv[r] = g * (acc2[mi][ni][r] + bia) + pv[r];
                *(f32x4*)((float*)outP + base) = wv;
            } else {
                const us4 pv = *(const us4*)((const unsigned short*)point + base);
                us4 wv;
#pragma unroll
                for (int r = 0; r < 4; ++r) wv[r] = f2b(g * (acc2[mi][ni][r] + bia) + b2f(pv[r]));
                *(us4*)((unsigned short*)outP + base) = wv;
            }
        }
}

extern "C" void kernel_launch(void* const* d_in, const int* in_sizes, int n_in,
                              void* d_out, int out_size, void* d_ws, size_t ws_size,
                              hipStream_t stream) {
    (void)in_sizes; (void)n_in; (void)out_size;
    const void* point = d_in[0];
    const void* text  = d_in[1];
    const void* Wt    = d_in[2];
    const void* bt    = d_in[3];
    const void* Wq    = d_in[4];
    const void* bq    = d_in[5];
    const void* Wk    = d_in[6];
    const void* bk    = d_in[7];
    const void* Wv    = d_in[8];
    const void* bv    = d_in[9];
    const void* W1    = d_in[10];
    const void* b1    = d_in[11];
    const void* W2    = d_in[12];
    const void* b2    = d_in[13];
    const void* gamma = d_in[14];

    char* ws = (char*)d_ws;
    const size_t SZ = (size_t)BB * NN * CC;   // 2 Mi bf16 = 4 MiB
    unsigned short* XTp  = (unsigned short*)(ws + 4096);
    unsigned short* XTf  = XTp + SZ;
    unsigned short* QT   = XTf + SZ;
    unsigned short* Vb   = QT + SZ;
    unsigned short* KT   = Vb + SZ;
    unsigned short* Wcvt = KT + SZ;           // 328,960 bf16 elems (~0.66 MB)
    float* Opart = (float*)(((uintptr_t)(Wcvt + 328960) + 255) & ~(uintptr_t)255);
    float* mlb   = Opart + (size_t)BB * HH * 2 * NN * HDD;
    unsigned short* AT = XTp;                 // SPLIT=1 fallback scratch (dead after k_qkv)

    size_t need2 = (size_t)((char*)(mlb + (size_t)BB * HH * 2 * NN * 2) - ws);
    bool split2 = ws_size >= need2;

    k_tf<<<dim3(NN / 64, CC / 64, BB + 1), 256, 0, stream>>>(
        point, text, Wt, bt, gamma, Wq, bq, Wk, bk, Wv, bv, W1, b1, W2, b2,
        Wcvt, XTp, XTf);
    k_qkv<<<dim3(1536), 64, 0, stream>>>(XTp, XTf, Wcvt, QT, KT, Vb);
    if (split2) {
        k_attn<2><<<dim3(NN / 128, BB * HH, 2), 256, 0, stream>>>(QT, KT, Vb, Opart, mlb, nullptr);
        k_mlp<2><<<dim3(BB * NN / 32), 256, 0, stream>>>(nullptr, Opart, mlb, Wcvt, point, gamma, d_out);
    } else {
        k_attn<1><<<dim3(NN / 128, BB * HH, 1), 256, 0, stream>>>(QT, KT, Vb, nullptr, nullptr, AT);
        k_mlp<1><<<dim3(BB * NN / 32), 256, 0, stream>>>(AT, nullptr, nullptr, Wcvt, point, gamma, d_out);
    }
}

// Round 17
// 128.610 us; speedup vs baseline: 1.5240x; 1.0006x over previous
//
#include <hip/hip_runtime.h>
#include <hip/hip_bf16.h>
#include <math.h>

#define BB   2
#define CC   256
#define NN   4096
#define DTXT 512
#define OO   256
#define HH   4
#define HDD  64

typedef __attribute__((ext_vector_type(4))) unsigned short us4;
typedef __attribute__((ext_vector_type(8))) short          bf16x8;
typedef __attribute__((ext_vector_type(4))) float          f32x4;
typedef __attribute__((ext_vector_type(2))) unsigned int   u32x2;

__device__ __forceinline__ float b2f(unsigned short u) {
    union { unsigned int i; float f; } x; x.i = ((unsigned int)u) << 16; return x.f;
}
__device__ __forceinline__ unsigned short f2b(float f) {
    union { float f; unsigned int i; } x; x.f = f;
    unsigned int r = (x.i + 0x7FFFu + ((x.i >> 16) & 1u)) >> 16;
    return (unsigned short)r;
}
__device__ __forceinline__ unsigned int cvtpk(float lo, float hi) {
    unsigned int r;
    asm volatile("v_cvt_pk_bf16_f32 %0, %1, %2" : "=v"(r) : "v"(lo), "v"(hi));
    return r;
}
__device__ __forceinline__ float loadIn(const void* p, size_t i, bool f32) {
    return f32 ? ((const float*)p)[i] : b2f(((const unsigned short*)p)[i]);
}
__device__ __forceinline__ bool inIsF32(const void* gammaP) {
    return ((const unsigned short*)gammaP)[0] == 0;
}
__device__ __forceinline__ unsigned short cvt1(const void* p, size_t i, bool f32) {
    return f32 ? f2b(((const float*)p)[i]) : ((const unsigned short*)p)[i];
}

// ---------- kernel 1: fused text-proj+GELU + transpose + weight-convert plane ----------
__global__ void __launch_bounds__(256) k_tf(const void* __restrict__ point,
                     const void* __restrict__ text,
                     const void* __restrict__ Wt,
                     const void* __restrict__ bt,
                     const void* __restrict__ gammaP,
                     const void* __restrict__ Wq, const void* __restrict__ bq,
                     const void* __restrict__ Wk, const void* __restrict__ bk,
                     const void* __restrict__ Wv, const void* __restrict__ bv,
                     const void* __restrict__ W1, const void* __restrict__ b1,
                     const void* __restrict__ W2, const void* __restrict__ b2,
                     unsigned short* __restrict__ wcvt,
                     unsigned short* __restrict__ xtp,
                     unsigned short* __restrict__ xtf) {
    bool f32in = inIsF32(gammaP);
    int tid = threadIdx.x;
    if (blockIdx.z == BB) {   // weight conversion plane (256 blocks)
        int id = blockIdx.y * 64 + blockIdx.x;
        int gid = id * 256 + tid;                 // 0..65535
        wcvt[gid]               = cvt1(Wq, gid, f32in);
        wcvt[65536 + gid]       = cvt1(Wk, gid, f32in);
        wcvt[131072 + gid]      = cvt1(Wv, gid, f32in);
        wcvt[196608 + gid]      = cvt1(W1, gid, f32in);
        wcvt[262144 + gid]      = cvt1(W2, gid, f32in);
        if (id == 0) {
            wcvt[327680 + tid] = cvt1(bq, tid, f32in);
            wcvt[327936 + tid] = cvt1(bk, tid, f32in);
            wcvt[328192 + tid] = cvt1(bv, tid, f32in);
            wcvt[328448 + tid] = cvt1(b1, tid, f32in);
            wcvt[328704 + tid] = cvt1(b2, tid, f32in);
        }
        return;
    }
    __shared__ float txt[DTXT];
    __shared__ float tv[64];
    __shared__ unsigned short tile[64][72];
    int b = blockIdx.z, c0 = blockIdx.y * 64, n0 = blockIdx.x * 64;
    int w = tid >> 6, l = tid & 63;

    for (int i = tid; i < DTXT; i += 256) txt[i] = loadIn(text, (size_t)b * DTXT + i, f32in);
    __syncthreads();
    {
        int c = c0 + w * 16 + (l >> 2);
        int q4 = (l & 3) * 128;
        float acc = 0.f;
        for (int it = 0; it < 128; it += 4) {
            int i = q4 + it;
            if (f32in) {
                f32x4 wv = *(const f32x4*)((const float*)Wt + (size_t)c * DTXT + i);
#pragma unroll
                for (int j = 0; j < 4; ++j) acc += wv[j] * txt[i + j];
            } else {
                us4 wv = *(const us4*)((const unsigned short*)Wt + (size_t)c * DTXT + i);
#pragma unroll
                for (int j = 0; j < 4; ++j) acc += b2f(wv[j]) * txt[i + j];
            }
        }
        acc += __shfl_xor(acc, 1);
        acc += __shfl_xor(acc, 2);
        if ((l & 3) == 0) {
            acc += loadIn(bt, c, f32in);
            tv[w * 16 + (l >> 2)] = 0.5f * acc * (1.f + erff(acc * 0.70710678118654752f));
        }
    }
#pragma unroll
    for (int it = 0; it < 2; ++it) {
        int cl = tid / 8 + it * 32;
        int nl = (tid % 8) * 8;
        size_t off = ((size_t)(b * CC + c0 + cl)) * NN + n0 + nl;
        unsigned short u[8];
        if (f32in) {
            const float* s = (const float*)point + off;
            f32x4 v0 = *(const f32x4*)s, v1 = *(const f32x4*)(s + 4);
#pragma unroll
            for (int j = 0; j < 4; ++j) { u[j] = f2b(v0[j]); u[4 + j] = f2b(v1[j]); }
        } else {
            const unsigned short* s = (const unsigned short*)point + off;
            us4 v0 = *(const us4*)s, v1 = *(const us4*)(s + 4);
#pragma unroll
            for (int j = 0; j < 4; ++j) { u[j] = v0[j]; u[4 + j] = v1[j]; }
        }
#pragma unroll
        for (int j = 0; j < 8; ++j) tile[cl][nl + j] = u[j];
    }
    __syncthreads();
#pragma unroll
    for (int it = 0; it < 2; ++it) {
        int nl = tid / 8 + it * 32;
        int cl = (tid % 8) * 8;
        size_t base = ((size_t)(b * NN + n0 + nl)) * CC + c0 + cl;
        us4 a0, a1, f0, f1;
#pragma unroll
        for (int j = 0; j < 4; ++j) {
            unsigned short u = tile[cl + j][nl];
            a0[j] = u; f0[j] = f2b(b2f(u) + tv[cl + j]);
        }
#pragma unroll
        for (int j = 0; j < 4; ++j) {
            unsigned short u = tile[cl + 4 + j][nl];
            a1[j] = u; f1[j] = f2b(b2f(u) + tv[cl + 4 + j]);
        }
        *(us4*)(xtp + base) = a0; *(us4*)(xtp + base + 4) = a1;
        *(us4*)(xtf + base) = f0; *(us4*)(xtf + base + 4) = f1;
    }
}

// ---------- one-wave 64x64 NT-GEMM tile body (bf16-only) ----------
__device__ __forceinline__ void gemm_tile64(
        const unsigned short* A, const unsigned short* Bm,
        const unsigned short* bias, bool biasRow, bool relu,
        int rowW, int colW, int K, int ldc,
        unsigned short* co, int l) {
    int lr = l & 15, lh = l >> 4;
    f32x4 acc[4][4] = {};
    for (int k0 = 0; k0 < K; k0 += 32) {
        bf16x8 af[4], bfr[4];
#pragma unroll
        for (int mi = 0; mi < 4; ++mi)
            af[mi] = *(const bf16x8*)(A + (size_t)(rowW + mi * 16 + lr) * K + k0 + 8 * lh);
#pragma unroll
        for (int ni = 0; ni < 4; ++ni)
            bfr[ni] = *(const bf16x8*)(Bm + (size_t)(colW + ni * 16 + lr) * K + k0 + 8 * lh);
#pragma unroll
        for (int mi = 0; mi < 4; ++mi)
#pragma unroll
            for (int ni = 0; ni < 4; ++ni)
                acc[mi][ni] = __builtin_amdgcn_mfma_f32_16x16x32_bf16(af[mi], bfr[ni], acc[mi][ni], 0, 0, 0);
    }
#pragma unroll
    for (int mi = 0; mi < 4; ++mi)
#pragma unroll
        for (int ni = 0; ni < 4; ++ni)
#pragma unroll
            for (int r = 0; r < 4; ++r) {
                int row = rowW + mi * 16 + lh * 4 + r;
                int col = colW + ni * 16 + lr;
                float v = acc[mi][ni][r] + b2f(bias[biasRow ? row : col]);
                if (relu) v = fmaxf(v, 0.f);
                co[(size_t)row * ldc + col] = f2b(v);
            }
}

// ---------- kernel 2: fused Q/K/V projections (bf16 ws weights) ----------
__global__ void __launch_bounds__(64) k_qkv(
        const unsigned short* __restrict__ XTp,
        const unsigned short* __restrict__ XTf,
        const unsigned short* __restrict__ wcvt,
        unsigned short* __restrict__ QT,
        unsigned short* __restrict__ KT,
        unsigned short* __restrict__ Vb) {
    const unsigned short* Wqb = wcvt;
    const unsigned short* Wkb = wcvt + 65536;
    const unsigned short* Wvb = wcvt + 131072;
    const unsigned short* bqb = wcvt + 327680;
    const unsigned short* bkb = wcvt + 327936;
    const unsigned short* bvb = wcvt + 328192;
    int bid = blockIdx.x, l = threadIdx.x;
    if (bid < 1024) {
        int t = bid & 511;
        bool isQ = bid < 512;
        int rowW = (t >> 2) * 64, colW = (t & 3) * 64;
        gemm_tile64(isQ ? XTp : XTf, isQ ? Wqb : Wkb,
                    isQ ? bqb : bkb, false, false,
                    rowW, colW, CC, OO, isQ ? QT : KT, l);
    } else {
        int t = bid - 1024;
        int b = t >> 8, r = t & 255;
        int rowW = (r & 3) * 64, colW = (r >> 2) * 64;
        gemm_tile64(Wvb, XTp + (size_t)b * NN * CC,
                    bvb, true, false,
                    rowW, colW, CC, NN, Vb + (size_t)b * OO * NN, l);
    }
}

// ---------- kernel 3: flash attention (R13/R15-passed config, byte-exact) ----------
template<int SPLIT>
__global__ void __launch_bounds__(256) k_attn(const unsigned short* __restrict__ QT,
                                              const unsigned short* __restrict__ KT,
                                              const unsigned short* __restrict__ Vb,
                                              float* __restrict__ Opart,
                                              float* __restrict__ mlb,
                                              unsigned short* __restrict__ AT) {
    const int NT = NN / SPLIT / 64;
    const float L2E = 1.44269504088896f;
    const float THR = 5.54517744448f;          // 8*ln2
    int n0 = blockIdx.x * 128;
    int bh = blockIdx.y;
    int b = bh >> 2, h = bh & 3;
    int sp = blockIdx.z;
    int kbase = sp * (NN / SPLIT);
    int tid = threadIdx.x;
    int w = tid >> 6, l = tid & 63, lr = l & 15, lh = l >> 4;

    __shared__ unsigned short Kl[2][64 * 72];
    __shared__ unsigned short Vl[2][64 * 72];
    __shared__ unsigned short Pl[4][32 * 72];

    const size_t qkBase = (size_t)b * NN * OO + h * HDD;
    const size_t vBase  = ((size_t)b * OO + h * HDD) * NN;

    const unsigned short* qrow0 = QT + qkBase + (size_t)(n0 + w * 32 + lr) * OO;
    const unsigned short* qrow1 = qrow0 + (size_t)16 * OO;
    bf16x8 qf00 = *(const bf16x8*)(qrow0 + 8 * lh);
    bf16x8 qf01 = *(const bf16x8*)(qrow0 + 32 + 8 * lh);
    bf16x8 qf10 = *(const bf16x8*)(qrow1 + 8 * lh);
    bf16x8 qf11 = *(const bf16x8*)(qrow1 + 32 + 8 * lh);

    int srow = tid >> 3;
    int scol = (tid & 7) * 8;
    const unsigned short* Kg = KT + qkBase + (size_t)(kbase + srow) * OO + scol;
    const unsigned short* Vg = Vb + vBase + (size_t)srow * NN + kbase + scol;
    int ldsW0 = srow * 72 + scol, ldsW1 = (srow + 32) * 72 + scol;

    bf16x8 ones;
#pragma unroll
    for (int j = 0; j < 8; ++j) ones[j] = (short)0x3F80;

    f32x4 oacc[2][4] = {};
    f32x4 lacc[2] = {};
    float mrun0 = -1e30f, mrun1 = -1e30f;
    const f32x4 zero = {0.f, 0.f, 0.f, 0.f};
    unsigned short* plw = &Pl[w][0];

    {
        bf16x8 ka0 = *(const bf16x8*)Kg;
        bf16x8 ka1 = *(const bf16x8*)(Kg + (size_t)32 * OO);
        bf16x8 va0 = *(const bf16x8*)Vg;
        bf16x8 va1 = *(const bf16x8*)(Vg + (size_t)32 * NN);
        *(bf16x8*)&Kl[0][ldsW0] = ka0; *(bf16x8*)&Kl[0][ldsW1] = ka1;
        *(bf16x8*)&Vl[0][ldsW0] = va0; *(bf16x8*)&Vl[0][ldsW1] = va1;
    }
    __syncthreads();

    for (int t = 0; t < NT; ++t) {
        int cur = t & 1;
        bf16x8 ka0, ka1, va0, va1;
        if (t < NT - 1) {
            const unsigned short* kg = Kg + (size_t)(t + 1) * 64 * OO;
            const unsigned short* vg = Vg + (t + 1) * 64;
            ka0 = *(const bf16x8*)kg;
            ka1 = *(const bf16x8*)(kg + (size_t)32 * OO);
            va0 = *(const bf16x8*)vg;
            va1 = *(const bf16x8*)(vg + (size_t)32 * NN);
        }
        f32x4 S0[4], S1[4];
#pragma unroll
        for (int s = 0; s < 4; ++s) {
            const unsigned short* kb = &Kl[cur][(16 * s + lr) * 72 + 8 * lh];
            bf16x8 k0 = *(const bf16x8*)kb;
            bf16x8 k1 = *(const bf16x8*)(kb + 32);
            S0[s] = __builtin_amdgcn_mfma_f32_16x16x32_bf16(k0, qf00, zero, 0, 0, 0);
            S0[s] = __builtin_amdgcn_mfma_f32_16x16x32_bf16(k1, qf01, S0[s], 0, 0, 0);
            S1[s] = __builtin_amdgcn_mfma_f32_16x16x32_bf16(k0, qf10, zero, 0, 0, 0);
            S1[s] = __builtin_amdgcn_mfma_f32_16x16x32_bf16(k1, qf11, S1[s], 0, 0, 0);
        }
        {
            float tm = -1e30f;
#pragma unroll
            for (int s = 0; s < 4; ++s)
                tm = fmaxf(tm, fmaxf(fmaxf(S0[s][0], S0[s][1]), fmaxf(S0[s][2], S0[s][3])));
            tm = fmaxf(tm, __shfl_xor(tm, 16));
            tm = fmaxf(tm, __shfl_xor(tm, 32));
            if (__any(tm > mrun0 + THR)) {
                float mn = fmaxf(mrun0, tm);
                float sc = exp2f((mrun0 - mn) * L2E);
                lacc[0] *= sc;
#pragma unroll
                for (int dt = 0; dt < 4; ++dt) oacc[0][dt] *= sc;
                mrun0 = mn;
            }
            float mL = mrun0 * L2E;
#pragma unroll
            for (int s = 0; s < 4; ++s) {
                float p0 = exp2f(__builtin_fmaf(S0[s][0], L2E, -mL));
                float p1 = exp2f(__builtin_fmaf(S0[s][1], L2E, -mL));
                float p2 = exp2f(__builtin_fmaf(S0[s][2], L2E, -mL));
                float p3 = exp2f(__builtin_fmaf(S0[s][3], L2E, -mL));
                u32x2 v; v[0] = cvtpk(p0, p1); v[1] = cvtpk(p2, p3);
                *(u32x2*)(plw + lr * 72 + s * 16 + 4 * lh) = v;
            }
        }
        {
            float tm = -1e30f;
#pragma unroll
            for (int s = 0; s < 4; ++s)
                tm = fmaxf(tm, fmaxf(fmaxf(S1[s][0], S1[s][1]), fmaxf(S1[s][2], S1[s][3])));
            tm = fmaxf(tm, __shfl_xor(tm, 16));
            tm = fmaxf(tm, __shfl_xor(tm, 32));
            if (__any(tm > mrun1 + THR)) {
                float mn = fmaxf(mrun1, tm);
                float sc = exp2f((mrun1 - mn) * L2E);
                lacc[1] *= sc;
#pragma unroll
                for (int dt = 0; dt < 4; ++dt) oacc[1][dt] *= sc;
                mrun1 = mn;
            }
            float mL = mrun1 * L2E;
#pragma unroll
            for (int s = 0; s < 4; ++s) {
                float p0 = exp2f(__builtin_fmaf(S1[s][0], L2E, -mL));
                float p1 = exp2f(__builtin_fmaf(S1[s][1], L2E, -mL));
                float p2 = exp2f(__builtin_fmaf(S1[s][2], L2E, -mL));
                float p3 = exp2f(__builtin_fmaf(S1[s][3], L2E, -mL));
                u32x2 v; v[0] = cvtpk(p0, p1); v[1] = cvtpk(p2, p3);
                *(u32x2*)(plw + (16 + lr) * 72 + s * 16 + 4 * lh) = v;
            }
        }
#pragma unroll
        for (int c = 0; c < 2; ++c) {
            bf16x8 pf0 = *(const bf16x8*)(plw + lr * 72 + c * 32 + 8 * lh);
            bf16x8 pf1 = *(const bf16x8*)(plw + (16 + lr) * 72 + c * 32 + 8 * lh);
            lacc[0] = __builtin_amdgcn_mfma_f32_16x16x32_bf16(ones, pf0, lacc[0], 0, 0, 0);
            lacc[1] = __builtin_amdgcn_mfma_f32_16x16x32_bf16(ones, pf1, lacc[1], 0, 0, 0);
#pragma unroll
            for (int dt = 0; dt < 4; ++dt) {
                bf16x8 vf = *(const bf16x8*)&Vl[cur][(dt * 16 + lr) * 72 + c * 32 + 8 * lh];
                oacc[0][dt] = __builtin_amdgcn_mfma_f32_16x16x32_bf16(vf, pf0, oacc[0][dt], 0, 0, 0);
                oacc[1][dt] = __builtin_amdgcn_mfma_f32_16x16x32_bf16(vf, pf1, oacc[1][dt], 0, 0, 0);
            }
        }
        if (t < NT - 1) {
            int nxt = cur ^ 1;
            *(bf16x8*)&Kl[nxt][ldsW0] = ka0; *(bf16x8*)&Kl[nxt][ldsW1] = ka1;
            *(bf16x8*)&Vl[nxt][ldsW0] = va0; *(bf16x8*)&Vl[nxt][ldsW1] = va1;
        }
        __syncthreads();
    }

#pragma unroll
    for (int h2 = 0; h2 < 2; ++h2) {
        float mrun = h2 ? mrun1 : mrun0;
        float lrun = lacc[h2][0];
        int nrow = n0 + w * 32 + 16 * h2 + lr;
        if (SPLIT == 1) {
            float invL = 1.f / lrun;
            unsigned short* orow = AT + ((size_t)b * NN + nrow) * OO + h * HDD;
#pragma unroll
            for (int dt = 0; dt < 4; ++dt) {
                us4 res;
#pragma unroll
                for (int r = 0; r < 4; ++r) res[r] = f2b(oacc[h2][dt][r] * invL);
                *(us4*)(orow + dt * 16 + 4 * lh) = res;
            }
        } else {
            size_t rbase = ((size_t)(b * HH + h) * SPLIT + sp) * NN + nrow;
#pragma unroll
            for (int dt = 0; dt < 4; ++dt)
                *(f32x4*)(Opart + rbase * HDD + dt * 16 + 4 * lh) = oacc[h2][dt];
            if (lh == 0) { mlb[rbase * 2] = mrun; mlb[rbase * 2 + 1] = lrun; }
        }
    }
}

// ---------- kernel 4: fused [amerge +] MLP1 + MLP2 + gamma/point epilogue ----------
template<int SPLIT>
__global__ void __launch_bounds__(256) k_mlp(
        const unsigned short* __restrict__ AT,
        const float* __restrict__ Opart,
        const float* __restrict__ mlb,
        const unsigned short* __restrict__ wcvt,
        const void* __restrict__ point,
        const void* __restrict__ gammaP,
        void* __restrict__ outP) {
    const unsigned short* W1b = wcvt + 196608;
    const unsigned short* W2b = wcvt + 262144;
    const unsigned short* b1b = wcvt + 328448;
    const unsigned short* b2b = wcvt + 328704;
    bool f32in = inIsF32(gammaP);
    float g = loadIn(gammaP, 0, f32in);
    __shared__ unsigned short X0l[32][264];
    __shared__ unsigned short X1l[32][264];
    int tid = threadIdx.x, w = tid >> 6, l = tid & 63;
    int lr = l & 15, lh = l >> 4;
    int row0 = blockIdx.x * 32;               // global row (b*NN + n)
    int colW = w * 64;
    int b = row0 >> 12;

    if (SPLIT == 2) {
        int r = tid & 31, hb = tid >> 5;      // hb 0..7
        int h = hb >> 1;
        int d0 = (hb & 1) * 32;
        int n = (row0 & (NN - 1)) + r;
        size_t rb0 = (((size_t)(b * HH + h)) * 2 + 0) * NN + n;
        size_t rb1 = (((size_t)(b * HH + h)) * 2 + 1) * NN + n;
        float m0 = mlb[rb0 * 2], l0 = mlb[rb0 * 2 + 1];
        float m1 = mlb[rb1 * 2], l1 = mlb[rb1 * 2 + 1];
        float M = fmaxf(m0, m1);
        float e0 = expf(m0 - M), e1 = expf(m1 - M);
        float invL = 1.f / (l0 * e0 + l1 * e1);
        float c0 = e0 * invL, c1 = e1 * invL;
        const float* O0 = Opart + rb0 * HDD + d0;
        const float* O1 = Opart + rb1 * HDD + d0;
#pragma unroll
        for (int j = 0; j < 8; ++j) {
            f32x4 a = *(const f32x4*)(O0 + 4 * j);
            f32x4 c = *(const f32x4*)(O1 + 4 * j);
            float v0 = a[0] * c0 + c[0] * c1;
            float v1 = a[1] * c0 + c[1] * c1;
            float v2 = a[2] * c0 + c[2] * c1;
            float v3 = a[3] * c0 + c[3] * c1;
            u32x2 pk; pk[0] = cvtpk(v0, v1); pk[1] = cvtpk(v2, v3);
            *(u32x2*)&X0l[r][hb * 32 + 4 * j] = pk;
        }
        __syncthreads();
    }

    // phase 1: X1 = relu(X0 * W1^T + b1)
    f32x4 acc1[2][4] = {};
    for (int k0 = 0; k0 < OO; k0 += 32) {
        bf16x8 af[2], bfr[4];
#pragma unroll
        for (int mi = 0; mi < 2; ++mi) {
            if (SPLIT == 2)
                af[mi] = *(const bf16x8*)&X0l[mi * 16 + lr][k0 + 8 * lh];
            else
                af[mi] = *(const bf16x8*)(AT + (size_t)(row0 + mi * 16 + lr) * OO + k0 + 8 * lh);
        }
#pragma unroll
        for (int ni = 0; ni < 4; ++ni)
            bfr[ni] = *(const bf16x8*)(W1b + (size_t)(colW + ni * 16 + lr) * OO + k0 + 8 * lh);
#pragma unroll
        for (int mi = 0; mi < 2; ++mi)
#pragma unroll
            for (int ni = 0; ni < 4; ++ni)
                acc1[mi][ni] = __builtin_amdgcn_mfma_f32_16x16x32_bf16(af[mi], bfr[ni], acc1[mi][ni], 0, 0, 0);
    }
#pragma unroll
    for (int mi = 0; mi < 2; ++mi)
#pragma unroll
        for (int ni = 0; ni < 4; ++ni) {
            int col = colW + ni * 16 + lr;
            float bia = b2f(b1b[col]);
#pragma unroll
            for (int r = 0; r < 4; ++r) {
                float v = acc1[mi][ni][r] + bia;
                X1l[mi * 16 + lh * 4 + r][col] = f2b(fmaxf(v, 0.f));
            }
        }
    __syncthreads();

    // phase 2: out = gamma*(X1*W2^T + b2) + point  (transposed write)
    f32x4 acc2[2][4] = {};
    for (int k0 = 0; k0 < OO; k0 += 32) {
        bf16x8 af[2], bfr[4];
#pragma unroll
        for (int mi = 0; mi < 2; ++mi)
            af[mi] = *(const bf16x8*)&X1l[mi * 16 + lr][k0 + 8 * lh];
#pragma unroll
        for (int ni = 0; ni < 4; ++ni)
            bfr[ni] = *(const bf16x8*)(W2b + (size_t)(colW + ni * 16 + lr) * OO + k0 + 8 * lh);
#pragma unroll
        for (int mi = 0; mi < 2; ++mi)
#pragma unroll
            for (int ni = 0; ni < 4; ++ni)
                acc2[mi][ni] = __builtin_amdgcn_mfma_f32_16x16x32_bf16(af[mi], bfr[ni], acc2[mi][ni], 0, 0, 0);
    }
#pragma unroll
    for (int mi = 0; mi < 2; ++mi)
#pragma unroll
        for (int ni = 0; ni < 4; ++ni) {
            int n = (row0 & (NN - 1)) + mi * 16 + lh * 4;
            int o = colW + ni * 16 + lr;
            size_t base = (size_t)b * OO * NN + (size_t)o * NN + n;
            float bia = b2f(b2b[o]);
            if (f32in) {
                const f32x4 pv = *(const f32x4*)((const float*)point + base);
                f32x4 wv;
#pragma unroll
                for (int r = 0; r < 4; ++r) wv[r] = g * (acc2[mi][ni][r] + bia) + pv[r];
                *(f32x4*)((float*)outP + base) = wv;
            } else {
                const us4 pv = *(const us4*)((const unsigned short*)point + base);
                us4 wv;
#pragma unroll
                for (int r = 0; r < 4; ++r) wv[r] = f2b(g * (acc2[mi][ni][r] + bia) + b2f(pv[r]));
                *(us4*)((unsigned short*)outP + base) = wv;
            }
        }
}

extern "C" void kernel_launch(void* const* d_in, const int* in_sizes, int n_in,
                              void* d_out, int out_size, void* d_ws, size_t ws_size,
                              hipStream_t stream) {
    (void)in_sizes; (void)n_in; (void)out_size;
    const void* point = d_in[0];
    const void* text  = d_in[1];
    const void* Wt    = d_in[2];
    const void* bt    = d_in[3];
    const void* Wq    = d_in[4];
    const void* bq    = d_in[5];
    const void* Wk    = d_in[6];
    const void* bk    = d_in[7];
    const void* Wv    = d_in[8];
    const void* bv    = d_in[9];
    const void* W1    = d_in[10];
    const void* b1    = d_in[11];
    const void* W2    = d_in[12];
    const void* b2    = d_in[13];
    const void* gamma = d_in[14];

    char* ws = (char*)d_ws;
    const size_t SZ = (size_t)BB * NN * CC;   // 2 Mi bf16 = 4 MiB
    unsigned short* XTp  = (unsigned short*)(ws + 4096);
    unsigned short* XTf  = XTp + SZ;
    unsigned short* QT   = XTf + SZ;
    unsigned short* Vb   = QT + SZ;
    unsigned short* KT   = Vb + SZ;
    unsigned short* Wcvt = KT + SZ;           // 328,960 bf16 elems (~0.66 MB)
    float* Opart = (float*)(((uintptr_t)(Wcvt + 328960) + 255) & ~(uintptr_t)255);
    float* mlb   = Opart + (size_t)BB * HH * 2 * NN * HDD;
    unsigned short* AT = XTp;                 // SPLIT=1 fallback scratch (dead after k_qkv)

    size_t need2 = (size_t)((char*)(mlb + (size_t)BB * HH * 2 * NN * 2) - ws);
    bool split2 = ws_size >= need2;

    k_tf<<<dim3(NN / 64, CC / 64, BB + 1), 256, 0, stream>>>(
        point, text, Wt, bt, gamma, Wq, bq, Wk, bk, Wv, bv, W1, b1, W2, b2,
        Wcvt, XTp, XTf);
    k_qkv<<<dim3(1536), 64, 0, stream>>>(XTp, XTf, Wcvt, QT, KT, Vb);
    if (split2) {
        k_attn<2><<<dim3(NN / 128, BB * HH, 2), 256, 0, stream>>>(QT, KT, Vb, Opart, mlb, nullptr);
        k_mlp<2><<<dim3(BB * NN / 32), 256, 0, stream>>>(nullptr, Opart, mlb, Wcvt, point, gamma, d_out);
    } else {
        k_attn<1><<<dim3(NN / 128, BB * HH, 1), 256, 0, stream>>>(QT, KT, Vb, nullptr, nullptr, AT);
        k_mlp<1><<<dim3(BB * NN / 32), 256, 0, stream>>>(AT, nullptr, nullptr, Wcvt, point, gamma, d_out);
    }
}